// Round 10
// baseline (442.165 us; speedup 1.0000x reference)
//
#include <hip/hip_runtime.h>
#include <hip/hip_bf16.h>
#include <math.h>

typedef __attribute__((ext_vector_type(8))) short short8;
typedef __attribute__((ext_vector_type(4))) short sv4;
typedef __attribute__((ext_vector_type(4))) float f32x4;

#define S_LEN 2048
#define NH 16
#define DMODEL 1024
#define DKH 64
// log2(e)/8 : scores tracked in exp2-units so exp() is a single v_exp_f32
#define SC 0.18033688011112042f

static __device__ __forceinline__ short f2bf(float f) {
  unsigned u = __builtin_bit_cast(unsigned, f);
  unsigned r = (u + 0x7fffu + ((u >> 16) & 1u)) >> 16;
  return (short)r;
}

static __device__ __forceinline__ float bf2f(short s) {
  return __builtin_bit_cast(float, ((unsigned)(unsigned short)s) << 16);
}

static __device__ __forceinline__ float e2(float x) { return __builtin_amdgcn_exp2f(x); }

static __device__ __forceinline__ void gld16(const void* g, void* l) {
  __builtin_amdgcn_global_load_lds((const __attribute__((address_space(1))) void*)g,
                                   (__attribute__((address_space(3))) void*)l, 16, 0, 0);
}

static __device__ __forceinline__ f32x4 mfma_bf16(short8 a, short8 b, f32x4 c) {
  return __builtin_amdgcn_mfma_f32_16x16x32_bf16(a, b, c, 0, 0, 0);
}

// ---------------- cast fp32 -> bf16 for q/k/v inputs ----------------
__global__ __launch_bounds__(256) void cast3_kernel(const float* __restrict__ q, const float* __restrict__ k,
                                                    const float* __restrict__ v,
                                                    short* __restrict__ oq, short* __restrict__ ok_,
                                                    short* __restrict__ ov) {
  const float* in = blockIdx.y == 0 ? q : (blockIdx.y == 1 ? k : v);
  short* out = blockIdx.y == 0 ? oq : (blockIdx.y == 1 ? ok_ : ov);
  int i = blockIdx.x * 256 + threadIdx.x;
  float4 f = ((const float4*)in)[i];
  sv4 o = {f2bf(f.x), f2bf(f.y), f2bf(f.z), f2bf(f.w)};
  ((sv4*)out)[i] = o;
}

// ---------------- bit-pack mask rows + all-ones summary ----------------
__global__ __launch_bounds__(256) void maskpack_kernel(const int* __restrict__ mask,
                                                       unsigned long long* __restrict__ mb,
                                                       unsigned* __restrict__ mall) {
  int row = blockIdx.x;  // b*S + q
  int w = threadIdx.x >> 6, lane = threadIdx.x & 63;
  const int* mp = mask + (size_t)row * S_LEN;
  __shared__ unsigned flags;
  if (threadIdx.x == 0) flags = 0;
  __syncthreads();
#pragma unroll
  for (int c = 0; c < 8; ++c) {
    int ci = w * 8 + c;
    unsigned long long bits = __ballot(mp[ci * 64 + lane] != 0);
    if (lane == 0) {
      mb[(size_t)row * 32 + ci] = bits;
      if (bits == ~0ull) atomicOr(&flags, 1u << ci);
    }
  }
  __syncthreads();
  if (threadIdx.x == 0) mall[row] = flags;
}

// ---------------- transpose-cast weights: out[n][k] = bf16(in[k][n]) ----------------
__global__ __launch_bounds__(256) void wtrans_kernel(const float* __restrict__ w0, const float* __restrict__ w1,
                                                     const float* __restrict__ w2, const float* __restrict__ w3,
                                                     short* __restrict__ o0, short* __restrict__ o1,
                                                     short* __restrict__ o2, short* __restrict__ o3) {
  const float* in = blockIdx.z == 0 ? w0 : blockIdx.z == 1 ? w1 : blockIdx.z == 2 ? w2 : w3;
  short* out = blockIdx.z == 0 ? o0 : blockIdx.z == 1 ? o1 : blockIdx.z == 2 ? o2 : o3;
  __shared__ float t[64][65];
  int tx = threadIdx.x & 63, ty = threadIdx.x >> 6;
  int bx = blockIdx.x * 64, by = blockIdx.y * 64;  // bx: n, by: k
#pragma unroll
  for (int i = 0; i < 16; ++i)
    t[ty + i * 4][tx] = in[(by + ty + i * 4) * DMODEL + bx + tx];
  __syncthreads();
#pragma unroll
  for (int i = 0; i < 16; ++i)
    out[(bx + ty + i * 4) * DMODEL + by + tx] = f2bf(t[tx][ty + i * 4]);
}

// ---------------- per-(b,h) max ||k_row|| over Kh ----------------
__global__ __launch_bounds__(256) void knorm_kernel(const short* __restrict__ Kh, float* __restrict__ maxKn) {
  int bh = blockIdx.x;
  int tid = threadIdx.x;
  float mx = 0.f;
  for (int r = tid; r < S_LEN; r += 256) {
    const short8* kp = (const short8*)(Kh + (size_t)(bh * S_LEN + r) * DKH);
    float s = 0.f;
#pragma unroll
    for (int i = 0; i < 8; ++i) {
      short8 v = kp[i];
#pragma unroll
      for (int e = 0; e < 8; ++e) {
        float f = bf2f(v[e]);
        s += f * f;
      }
    }
    mx = fmaxf(mx, s);
  }
#pragma unroll
  for (int d = 1; d < 64; d <<= 1) mx = fmaxf(mx, __shfl_xor(mx, d));
  __shared__ float red[4];
  if ((tid & 63) == 0) red[tid >> 6] = mx;
  __syncthreads();
  if (tid == 0) maxKn[bh] = sqrtf(fmaxf(fmaxf(red[0], red[1]), fmaxf(red[2], red[3])));
}

// ---------------- batched Q/K/V projection GEMM (double-buffered) ----------------
__global__ __launch_bounds__(256) void proj_qkv(const short* __restrict__ Aq, const short* __restrict__ Ak,
                                                const short* __restrict__ Av,
                                                const short* __restrict__ Wq, const short* __restrict__ Wk,
                                                const short* __restrict__ Wv,
                                                const float* __restrict__ bq, const float* __restrict__ bk,
                                                const float* __restrict__ bv,
                                                short* __restrict__ Qh, short* __restrict__ Kh,
                                                short* __restrict__ Vt) {
  const int z = blockIdx.z;
  const short* A = z == 0 ? Aq : z == 1 ? Ak : Av;
  const short* W = z == 0 ? Wq : z == 1 ? Wk : Wv;
  const float* bias = z == 0 ? bq : z == 1 ? bk : bv;

  const int tid = threadIdx.x;
  const int wid = tid >> 6, lane = tid & 63;
  const int g = lane >> 4, li = lane & 15;
  const int wm = (wid >> 1) * 64, wn = (wid & 1) * 64;
  const int bn = blockIdx.x * 128, bm = blockIdx.y * 128;

  __shared__ __align__(16) short As[2][4096];
  __shared__ __align__(16) short Bs[2][4096];
  __shared__ __align__(16) short T2[64 * 136];

  auto stage = [&](int ks, int pb) {
    const int k0 = ks * 32;
#pragma unroll
    for (int i = 0; i < 2; ++i) {
      int slot = i * 256 + tid;
      int r = slot >> 2, pos = slot & 3;
      int lch = pos ^ ((r >> 1) & 3);
      gld16(A + (size_t)(bm + r) * DMODEL + k0 + lch * 8, As[pb] + slot * 8);
      gld16(W + (size_t)(bn + r) * DMODEL + k0 + lch * 8, Bs[pb] + slot * 8);
    }
  };

  f32x4 acc[4][4];
#pragma unroll
  for (int m = 0; m < 4; ++m)
#pragma unroll
    for (int n = 0; n < 4; ++n) acc[m][n] = (f32x4){0.f, 0.f, 0.f, 0.f};

  stage(0, 0);
  __syncthreads();
  for (int ks = 0; ks < 32; ++ks) {
    const int cur = ks & 1;
    if (ks + 1 < 32) stage(ks + 1, cur ^ 1);
    short8 av[4], bv4[4];
#pragma unroll
    for (int m = 0; m < 4; ++m) {
      int r = wm + m * 16 + li;
      av[m] = *(const short8*)(As[cur] + r * 32 + (g ^ ((r >> 1) & 3)) * 8);
    }
#pragma unroll
    for (int n = 0; n < 4; ++n) {
      int r = wn + n * 16 + li;
      bv4[n] = *(const short8*)(Bs[cur] + r * 32 + (g ^ ((r >> 1) & 3)) * 8);
    }
    __builtin_amdgcn_s_setprio(1);
#pragma unroll
    for (int m = 0; m < 4; ++m)
#pragma unroll
      for (int n = 0; n < 4; ++n) acc[m][n] = mfma_bf16(av[m], bv4[n], acc[m][n]);
    __builtin_amdgcn_s_setprio(0);
    __syncthreads();
  }

  if (z < 2) {
    short* out = z == 0 ? Qh : Kh;
#pragma unroll
    for (int n = 0; n < 4; ++n) {
      int col = bn + wn + n * 16 + li;
      float bb = bias[col];
      int h = col >> 6, dk = col & 63;
#pragma unroll
      for (int m = 0; m < 4; ++m)
#pragma unroll
        for (int j = 0; j < 4; ++j) {
          int row = bm + wm + m * 16 + g * 4 + j;
          int b_ = row >> 11, s_ = row & 2047;
          out[(size_t)((b_ * NH + h) * S_LEN + s_) * DKH + dk] = f2bf(acc[m][n][j] + bb);
        }
    }
  } else {  // V^T via two-pass LDS transpose, coalesced along s
    short* out = Vt;
    const int b_ = bm >> 11;
    const int sbase = bm & 2047;
#pragma unroll
    for (int ph = 0; ph < 2; ++ph) {
      __syncthreads();
      if ((wid & 1) == ph) {
#pragma unroll
        for (int n = 0; n < 4; ++n) {
          int colL = n * 16 + li;
          float bb = bias[bn + ph * 64 + colL];
#pragma unroll
          for (int m = 0; m < 4; ++m)
#pragma unroll
            for (int j = 0; j < 4; ++j) {
              int rowL = wm + m * 16 + g * 4 + j;
              T2[colL * 136 + rowL] = f2bf(acc[m][n][j] + bb);
            }
        }
      }
      __syncthreads();
      int dr = tid >> 2, qc = tid & 3;
      int nglob = bn + ph * 64 + dr;
      int h = nglob >> 6, dk = nglob & 63;
      short* op = out + (size_t)((b_ * NH + h) * DKH + dk) * S_LEN + sbase + qc * 32;
      const short* tp = T2 + dr * 136 + qc * 32;
#pragma unroll
      for (int i = 0; i < 4; ++i) *(short8*)(op + i * 8) = *(const short8*)(tp + i * 8);
    }
  }
}

// ---------------- output projection GEMM: A = xb0 + xb1 (reg-staged), fp32 out ----------------
__global__ __launch_bounds__(256) void proj_out(const short* __restrict__ A0, const short* __restrict__ A1,
                                                const short* __restrict__ W,
                                                const float* __restrict__ bias, float* __restrict__ out) {
  const int tid = threadIdx.x;
  const int wid = tid >> 6, lane = tid & 63;
  const int g = lane >> 4, li = lane & 15;
  const int wm = (wid >> 1) * 64, wn = (wid & 1) * 64;
  const int bn = blockIdx.x * 128, bm = blockIdx.y * 128;

  __shared__ __align__(16) short As[2][4096];
  __shared__ __align__(16) short Bs[2][4096];

  auto stage = [&](int ks, int pb) {
    const int k0 = ks * 32;
#pragma unroll
    for (int i = 0; i < 2; ++i) {
      int slot = i * 256 + tid;
      int r = slot >> 2, pos = slot & 3;
      int lch = pos ^ ((r >> 1) & 3);
      // A path: reg-stage xb0 + xb1 (same swizzled layout as gld16 produced)
      short8 a0 = *(const short8*)(A0 + (size_t)(bm + r) * DMODEL + k0 + lch * 8);
      short8 a1 = *(const short8*)(A1 + (size_t)(bm + r) * DMODEL + k0 + lch * 8);
      short8 s;
#pragma unroll
      for (int e = 0; e < 8; ++e) s[e] = f2bf(bf2f(a0[e]) + bf2f(a1[e]));
      *(short8*)(As[pb] + slot * 8) = s;
      gld16(W + (size_t)(bn + r) * DMODEL + k0 + lch * 8, Bs[pb] + slot * 8);
    }
  };

  f32x4 acc[4][4];
#pragma unroll
  for (int m = 0; m < 4; ++m)
#pragma unroll
    for (int n = 0; n < 4; ++n) acc[m][n] = (f32x4){0.f, 0.f, 0.f, 0.f};

  stage(0, 0);
  __syncthreads();
  for (int ks = 0; ks < 32; ++ks) {
    const int cur = ks & 1;
    if (ks + 1 < 32) stage(ks + 1, cur ^ 1);
    short8 av[4], bv4[4];
#pragma unroll
    for (int m = 0; m < 4; ++m) {
      int r = wm + m * 16 + li;
      av[m] = *(const short8*)(As[cur] + r * 32 + (g ^ ((r >> 1) & 3)) * 8);
    }
#pragma unroll
    for (int n = 0; n < 4; ++n) {
      int r = wn + n * 16 + li;
      bv4[n] = *(const short8*)(Bs[cur] + r * 32 + (g ^ ((r >> 1) & 3)) * 8);
    }
    __builtin_amdgcn_s_setprio(1);
#pragma unroll
    for (int m = 0; m < 4; ++m)
#pragma unroll
      for (int n = 0; n < 4; ++n) acc[m][n] = mfma_bf16(av[m], bv4[n], acc[m][n]);
    __builtin_amdgcn_s_setprio(0);
    __syncthreads();
  }

#pragma unroll
  for (int n = 0; n < 4; ++n) {
    int col = bn + wn + n * 16 + li;
    float bb = bias[col];
#pragma unroll
    for (int m = 0; m < 4; ++m)
#pragma unroll
      for (int j = 0; j < 4; ++j) {
        int row = bm + wm + m * 16 + g * 4 + j;
        out[(size_t)row * DMODEL + col] = acc[m][n][j] + bb;
      }
  }
}

// ---------------- attention pass 1: l = sum exp2(s - M2) (R6-validated sweep1) ----------------
__global__ __launch_bounds__(256) void attn_pass1(const short* __restrict__ Qh, const short* __restrict__ Kh,
                                                  const unsigned long long* __restrict__ maskb,
                                                  const unsigned* __restrict__ mall,
                                                  const float* __restrict__ maxKn,
                                                  float* __restrict__ lrow) {
  const int tid = threadIdx.x;
  const int wid = tid >> 6, lane = tid & 63;
  const int g = lane >> 4, li = lane & 15;
  int swz = (blockIdx.x & 7) * 128 + (blockIdx.x >> 3);
  const int qblk = swz & 31;
  const int rest = swz >> 5;
  const int h = rest & 15, b = rest >> 4;
  const int bh = b * NH + h;
  const int q0 = qblk * 64 + wid * 16;

  const short* qptr = Qh + (size_t)(bh * S_LEN + q0 + li) * DKH;
  const short8 aq0 = *(const short8*)(qptr + g * 8);
  const short8 aq1 = *(const short8*)(qptr + 32 + g * 8);

  float qn2 = 0.f;
#pragma unroll
  for (int e = 0; e < 8; ++e) {
    float f0 = bf2f(aq0[e]), f1 = bf2f(aq1[e]);
    qn2 += f0 * f0 + f1 * f1;
  }
  qn2 += __shfl_xor(qn2, 16);
  qn2 += __shfl_xor(qn2, 32);
  const float mk = maxKn[bh];

  float M2[4], lsum[4];
  unsigned ms[4];
#pragma unroll
  for (int j = 0; j < 4; ++j) {
    float qn = __shfl(qn2, g * 4 + j);
    M2[j] = sqrtf(qn) * mk * SC + 1.0f;  // Cauchy-Schwarz upper bound, +1 margin
    lsum[j] = 0.f;
    ms[j] = mall[b * S_LEN + q0 + g * 4 + j];
  }

  __shared__ __align__(16) short SB[16384];  // two 128x64 K bufs

  auto stage1 = [&](int t) {
    short* dst = SB + (t & 1) * 8192;
#pragma unroll
    for (int i = 0; i < 4; ++i) {
      int slot = i * 256 + tid;
      int r = slot >> 3, pos = slot & 7;
      int lch = pos ^ (r & 7);
      gld16(Kh + (size_t)(bh * S_LEN + t * 128 + r) * DKH + lch * 8, dst + slot * 8);
    }
  };

  stage1(0);
  __syncthreads();
  for (int t = 0; t < 16; ++t) {
    const short* Kc = SB + (t & 1) * 8192;
    if (t + 1 < 16) stage1(t + 1);
#pragma unroll
    for (int half = 0; half < 2; ++half) {
      f32x4 acc[4];
      __builtin_amdgcn_s_setprio(1);
#pragma unroll
      for (int nf = 0; nf < 4; ++nf) {
        acc[nf] = (f32x4){0.f, 0.f, 0.f, 0.f};
        int rB = half * 64 + nf * 16 + li;
        const short8 b0 = *(const short8*)(Kc + rB * 64 + ((0 + g) ^ (rB & 7)) * 8);
        const short8 b1 = *(const short8*)(Kc + rB * 64 + ((4 + g) ^ (rB & 7)) * 8);
        acc[nf] = mfma_bf16(aq0, b0, acc[nf]);
        acc[nf] = mfma_bf16(aq1, b1, acc[nf]);
      }
      __builtin_amdgcn_s_setprio(0);
#pragma unroll
      for (int j = 0; j < 4; ++j) {
        float s0 = acc[0][j] * SC - M2[j];
        float s1 = acc[1][j] * SC - M2[j];
        float s2 = acc[2][j] * SC - M2[j];
        float s3 = acc[3][j] * SC - M2[j];
        if (!((ms[j] >> (t * 2 + half)) & 1)) {
          unsigned long long mb = maskb[(size_t)(b * S_LEN + q0 + g * 4 + j) * 32 + t * 2 + half];
          if (!((mb >> li) & 1)) s0 = -INFINITY;
          if (!((mb >> (16 + li)) & 1)) s1 = -INFINITY;
          if (!((mb >> (32 + li)) & 1)) s2 = -INFINITY;
          if (!((mb >> (48 + li)) & 1)) s3 = -INFINITY;
        }
        lsum[j] += e2(s0) + e2(s1) + e2(s2) + e2(s3);
      }
    }
    __syncthreads();
  }
#pragma unroll
  for (int d = 1; d < 16; d <<= 1)
#pragma unroll
    for (int j = 0; j < 4; ++j) lsum[j] += __shfl_xor(lsum[j], d);
  if (li == 0) {
#pragma unroll
    for (int j = 0; j < 4; ++j) lrow[bh * S_LEN + q0 + g * 4 + j] = lsum[j];
  }
}

// ---------------- attention pass 2: k-split x2, p write + partial PV ----------------
__global__ __launch_bounds__(256, 5) void attn_pass2(const short* __restrict__ Qh, const short* __restrict__ Kh,
                                                     const short* __restrict__ Vt,
                                                     const unsigned long long* __restrict__ maskb,
                                                     const unsigned* __restrict__ mall,
                                                     const float* __restrict__ maxKn,
                                                     const float* __restrict__ lrow,
                                                     float* __restrict__ pattn,
                                                     short* __restrict__ xb0, short* __restrict__ xb1) {
  const int tid = threadIdx.x;
  const int wid = tid >> 6, lane = tid & 63;
  const int g = lane >> 4, li = lane & 15;
  // XCD-chunked swizzle (2048 % 8 == 0, bijective); one XCD chunk = 4 bh values
  int swz = (blockIdx.x & 7) * 256 + (blockIdx.x >> 3);
  const int qblk = swz & 31;
  const int kh = (swz >> 5) & 1;
  const int bhi = swz >> 6;
  const int h = bhi & 15, b = bhi >> 4;
  const int bh = b * NH + h;
  const int q0 = qblk * 64 + wid * 16;
  const int kbase = kh * 1024;

  const short* qptr = Qh + (size_t)(bh * S_LEN + q0 + li) * DKH;
  const short8 aq0 = *(const short8*)(qptr + g * 8);
  const short8 aq1 = *(const short8*)(qptr + 32 + g * 8);

  float qn2 = 0.f;
#pragma unroll
  for (int e = 0; e < 8; ++e) {
    float f0 = bf2f(aq0[e]), f1 = bf2f(aq1[e]);
    qn2 += f0 * f0 + f1 * f1;
  }
  qn2 += __shfl_xor(qn2, 16);
  qn2 += __shfl_xor(qn2, 32);
  const float mk = maxKn[bh];

  float M2[4], linv[4];
  unsigned ms[4];
#pragma unroll
  for (int j = 0; j < 4; ++j) {
    float qn = __shfl(qn2, g * 4 + j);
    M2[j] = sqrtf(qn) * mk * SC + 1.0f;  // must match pass1 bit-exactly (same ops)
    linv[j] = 1.f / lrow[bh * S_LEN + q0 + g * 4 + j];
    ms[j] = mall[b * S_LEN + q0 + g * 4 + j];
  }

  // 24 KB LDS: K 0..4096, V 4096..8192, Ps 8192..12288 (shorts)
  __shared__ __align__(16) short SB[12288];

  f32x4 accx[4];
#pragma unroll
  for (int nf = 0; nf < 4; ++nf) accx[nf] = (f32x4){0.f, 0.f, 0.f, 0.f};

  for (int t = 0; t < 16; ++t) {
    const int ktg = kh * 16 + t;       // global 64-tile index
    const int k0 = kbase + t * 64;
    // single-buffer staging; TLP across 5-6 co-resident blocks hides the latency
#pragma unroll
    for (int i = 0; i < 2; ++i) {
      int slot = i * 256 + tid;
      int r = slot >> 3, pos = slot & 7;
      int lch = pos ^ (r & 7);
      gld16(Kh + (size_t)(bh * S_LEN + k0 + r) * DKH + lch * 8, SB + slot * 8);
      gld16(Vt + (size_t)(bh * DKH + r) * S_LEN + k0 + lch * 8, SB + 4096 + slot * 8);
    }
    __syncthreads();

    const short* Kc = SB;
    const short* Vc = SB + 4096;
    short* Ps = SB + 8192;

    f32x4 acc[4];
    __builtin_amdgcn_s_setprio(1);
#pragma unroll
    for (int nf = 0; nf < 4; ++nf) {
      acc[nf] = (f32x4){0.f, 0.f, 0.f, 0.f};
      int rB = nf * 16 + li;
      const short8 b0 = *(const short8*)(Kc + rB * 64 + ((0 + g) ^ (rB & 7)) * 8);
      const short8 b1 = *(const short8*)(Kc + rB * 64 + ((4 + g) ^ (rB & 7)) * 8);
      acc[nf] = mfma_bf16(aq0, b0, acc[nf]);
      acc[nf] = mfma_bf16(aq1, b1, acc[nf]);
    }
    __builtin_amdgcn_s_setprio(0);

    // softmax -> per-wave bf16 NORMALIZED p tile in LDS (swizzled)
#pragma unroll
    for (int j = 0; j < 4; ++j) {
      const int qrow = q0 + g * 4 + j;
      bool full = (ms[j] >> ktg) & 1;
      unsigned long long mb = full ? ~0ull : maskb[(size_t)(b * S_LEN + qrow) * 32 + ktg];
      const int row = g * 4 + j;
#pragma unroll
      for (int nf = 0; nf < 4; ++nf) {
        float s = acc[nf][j] * SC - M2[j];
        if (!full && !((mb >> (nf * 16 + li)) & 1)) s = -INFINITY;
        float p = e2(s) * linv[j];
        int col = nf * 16 + li;
        int sidx = row * 64 + (((col >> 3) ^ (row & 7)) * 8) + (col & 7);
        Ps[wid * 1024 + sidx] = f2bf(p);
      }
    }

    // PV on normalized p
    const short8 pa0 = *(const short8*)(Ps + wid * 1024 + li * 64 + ((0 + g) ^ (li & 7)) * 8);
    const short8 pa1 = *(const short8*)(Ps + wid * 1024 + li * 64 + ((4 + g) ^ (li & 7)) * 8);
    __builtin_amdgcn_s_setprio(1);
#pragma unroll
    for (int nf = 0; nf < 4; ++nf) {
      int rv = nf * 16 + li;
      const short8 v0 = *(const short8*)(Vc + rv * 64 + ((0 + g) ^ (rv & 7)) * 8);
      const short8 v1 = *(const short8*)(Vc + rv * 64 + ((4 + g) ^ (rv & 7)) * 8);
      accx[nf] = mfma_bf16(pa0, v0, accx[nf]);
      accx[nf] = mfma_bf16(pa1, v1, accx[nf]);
    }
    __builtin_amdgcn_s_setprio(0);

    // p_attn write AFTER PV (R6-validated order)
    {
      const int rg = lane >> 4;
      const int c = (lane & 15) * 4;
#pragma unroll
      for (int s = 0; s < 4; ++s) {
        int r = s * 4 + rg;
        int chunk = (c >> 3) ^ (r & 7);
        sv4 pv4 = *(const sv4*)(Ps + wid * 1024 + r * 64 + chunk * 8 + (c & 7));
        f32x4 w4;
        w4[0] = bf2f(pv4[0]);
        w4[1] = bf2f(pv4[1]);
        w4[2] = bf2f(pv4[2]);
        w4[3] = bf2f(pv4[3]);
        *(f32x4*)(pattn + (size_t)(bh * S_LEN + q0 + r) * S_LEN + k0 + c) = w4;
      }
    }
    __syncthreads();
  }

  short* xb = kh ? xb1 : xb0;
#pragma unroll
  for (int nf = 0; nf < 4; ++nf) {
    int d = nf * 16 + li;
#pragma unroll
    for (int j = 0; j < 4; ++j) {
      int q = q0 + g * 4 + j;
      xb[(size_t)(b * S_LEN + q) * DMODEL + h * DKH + d] = f2bf(accx[nf][j]);
    }
  }
}

extern "C" void kernel_launch(void* const* d_in, const int* in_sizes, int n_in,
                              void* d_out, int out_size, void* d_ws, size_t ws_size,
                              hipStream_t stream) {
  (void)in_sizes; (void)n_in; (void)out_size; (void)ws_size;
  const float* query = (const float*)d_in[0];
  const float* key = (const float*)d_in[1];
  const float* value = (const float*)d_in[2];
  const int* mask = (const int*)d_in[3];
  const float* wq = (const float*)d_in[4];
  const float* bq = (const float*)d_in[5];
  const float* wk = (const float*)d_in[6];
  const float* bk = (const float*)d_in[7];
  const float* wv = (const float*)d_in[8];
  const float* bv = (const float*)d_in[9];
  const float* wo = (const float*)d_in[10];
  const float* bo = (const float*)d_in[11];

  char* ws = (char*)d_ws;
  const size_t MB = 1u << 20;
  short* qb = (short*)(ws + 0 * MB);
  short* kb = (short*)(ws + 8 * MB);
  short* vb = (short*)(ws + 16 * MB);
  short* wqT = (short*)(ws + 24 * MB);
  short* wkT = (short*)(ws + 26 * MB);
  short* wvT = (short*)(ws + 28 * MB);
  short* woT = (short*)(ws + 30 * MB);
  short* Qh = (short*)(ws + 32 * MB);
  short* Kh = (short*)(ws + 40 * MB);
  short* Vt = (short*)(ws + 48 * MB);
  float* maxKn = (float*)(ws + 56 * MB);
  unsigned* mall = (unsigned*)(ws + 56 * MB + 64 * 1024);
  // regions dead after proj_qkv are reused:
  unsigned long long* maskb = (unsigned long long*)(ws + 16 * MB);  // vb region (1 MB)
  float* lrow = (float*)(ws + 17 * MB);                             // vb region (+256 KB)
  short* xb0 = (short*)(ws + 0 * MB);                               // qb region (8 MB)
  short* xb1 = (short*)(ws + 8 * MB);                               // kb region (8 MB)

  float* out_x = (float*)d_out;
  float* out_p = (float*)d_out + 4194304;

  cast3_kernel<<<dim3(4096, 3), 256, 0, stream>>>(query, key, value, qb, kb, vb);
  wtrans_kernel<<<dim3(16, 16, 4), 256, 0, stream>>>(wq, wk, wv, wo, wqT, wkT, wvT, woT);
  proj_qkv<<<dim3(8, 32, 3), 256, 0, stream>>>(qb, kb, vb, wqT, wkT, wvT, bq, bk, bv, Qh, Kh, Vt);
  maskpack_kernel<<<dim3(4096), 256, 0, stream>>>(mask, maskb, mall);
  knorm_kernel<<<dim3(32), 256, 0, stream>>>(Kh, maxKn);
  attn_pass1<<<dim3(1024), 256, 0, stream>>>(Qh, Kh, maskb, mall, maxKn, lrow);
  attn_pass2<<<dim3(2048), 256, 0, stream>>>(Qh, Kh, Vt, maskb, mall, maxKn, lrow, out_p, xb0, xb1);
  proj_out<<<dim3(8, 32), 256, 0, stream>>>(xb0, xb1, woT, bo, out_x);
}

// Round 11
// 281.191 us; speedup vs baseline: 1.5725x; 1.5725x over previous
//
#include <hip/hip_runtime.h>
#include <hip/hip_bf16.h>
#include <math.h>

typedef __attribute__((ext_vector_type(8))) short short8;
typedef __attribute__((ext_vector_type(4))) short sv4;
typedef __attribute__((ext_vector_type(4))) float f32x4;

#define S_LEN 2048
#define NH 16
#define DMODEL 1024
#define DKH 64
// log2(e)/8 : scores tracked in exp2-units so exp() is a single v_exp_f32
#define SC 0.18033688011112042f

static __device__ __forceinline__ short f2bf(float f) {
  unsigned u = __builtin_bit_cast(unsigned, f);
  unsigned r = (u + 0x7fffu + ((u >> 16) & 1u)) >> 16;
  return (short)r;
}

static __device__ __forceinline__ float bf2f(short s) {
  return __builtin_bit_cast(float, ((unsigned)(unsigned short)s) << 16);
}

static __device__ __forceinline__ float e2(float x) { return __builtin_amdgcn_exp2f(x); }

static __device__ __forceinline__ void gld16(const void* g, void* l) {
  __builtin_amdgcn_global_load_lds((const __attribute__((address_space(1))) void*)g,
                                   (__attribute__((address_space(3))) void*)l, 16, 0, 0);
}

static __device__ __forceinline__ f32x4 mfma_bf16(short8 a, short8 b, f32x4 c) {
  return __builtin_amdgcn_mfma_f32_16x16x32_bf16(a, b, c, 0, 0, 0);
}

// ---------------- cast fp32 -> bf16 for q/k/v inputs ----------------
__global__ __launch_bounds__(256) void cast3_kernel(const float* __restrict__ q, const float* __restrict__ k,
                                                    const float* __restrict__ v,
                                                    short* __restrict__ oq, short* __restrict__ ok_,
                                                    short* __restrict__ ov) {
  const float* in = blockIdx.y == 0 ? q : (blockIdx.y == 1 ? k : v);
  short* out = blockIdx.y == 0 ? oq : (blockIdx.y == 1 ? ok_ : ov);
  int i = blockIdx.x * 256 + threadIdx.x;
  float4 f = ((const float4*)in)[i];
  sv4 o = {f2bf(f.x), f2bf(f.y), f2bf(f.z), f2bf(f.w)};
  ((sv4*)out)[i] = o;
}

// ---------------- bit-pack mask rows + all-ones summary ----------------
__global__ __launch_bounds__(256) void maskpack_kernel(const int* __restrict__ mask,
                                                       unsigned long long* __restrict__ mb,
                                                       unsigned* __restrict__ mall) {
  int row = blockIdx.x;  // b*S + q
  int w = threadIdx.x >> 6, lane = threadIdx.x & 63;
  const int* mp = mask + (size_t)row * S_LEN;
  __shared__ unsigned flags;
  if (threadIdx.x == 0) flags = 0;
  __syncthreads();
#pragma unroll
  for (int c = 0; c < 8; ++c) {
    int ci = w * 8 + c;
    unsigned long long bits = __ballot(mp[ci * 64 + lane] != 0);
    if (lane == 0) {
      mb[(size_t)row * 32 + ci] = bits;
      if (bits == ~0ull) atomicOr(&flags, 1u << ci);
    }
  }
  __syncthreads();
  if (threadIdx.x == 0) mall[row] = flags;
}

// ---------------- transpose-cast weights: out[n][k] = bf16(in[k][n]) ----------------
__global__ __launch_bounds__(256) void wtrans_kernel(const float* __restrict__ w0, const float* __restrict__ w1,
                                                     const float* __restrict__ w2, const float* __restrict__ w3,
                                                     short* __restrict__ o0, short* __restrict__ o1,
                                                     short* __restrict__ o2, short* __restrict__ o3) {
  const float* in = blockIdx.z == 0 ? w0 : blockIdx.z == 1 ? w1 : blockIdx.z == 2 ? w2 : w3;
  short* out = blockIdx.z == 0 ? o0 : blockIdx.z == 1 ? o1 : blockIdx.z == 2 ? o2 : o3;
  __shared__ float t[64][65];
  int tx = threadIdx.x & 63, ty = threadIdx.x >> 6;
  int bx = blockIdx.x * 64, by = blockIdx.y * 64;  // bx: n, by: k
#pragma unroll
  for (int i = 0; i < 16; ++i)
    t[ty + i * 4][tx] = in[(by + ty + i * 4) * DMODEL + bx + tx];
  __syncthreads();
#pragma unroll
  for (int i = 0; i < 16; ++i)
    out[(bx + ty + i * 4) * DMODEL + by + tx] = f2bf(t[tx][ty + i * 4]);
}

// ---------------- per-(b,h) max ||k_row|| over Kh ----------------
__global__ __launch_bounds__(256) void knorm_kernel(const short* __restrict__ Kh, float* __restrict__ maxKn) {
  int bh = blockIdx.x;
  int tid = threadIdx.x;
  float mx = 0.f;
  for (int r = tid; r < S_LEN; r += 256) {
    const short8* kp = (const short8*)(Kh + (size_t)(bh * S_LEN + r) * DKH);
    float s = 0.f;
#pragma unroll
    for (int i = 0; i < 8; ++i) {
      short8 v = kp[i];
#pragma unroll
      for (int e = 0; e < 8; ++e) {
        float f = bf2f(v[e]);
        s += f * f;
      }
    }
    mx = fmaxf(mx, s);
  }
#pragma unroll
  for (int d = 1; d < 64; d <<= 1) mx = fmaxf(mx, __shfl_xor(mx, d));
  __shared__ float red[4];
  if ((tid & 63) == 0) red[tid >> 6] = mx;
  __syncthreads();
  if (tid == 0) maxKn[bh] = sqrtf(fmaxf(fmaxf(red[0], red[1]), fmaxf(red[2], red[3])));
}

// ---------------- batched Q/K/V projection GEMM (double-buffered) ----------------
// z=0 (Q), z=1 (K): out bf16 [B,H,S,DK].  z=2 (V): out bf16 [B,H,DK,S] (V^T).
__global__ __launch_bounds__(256) void proj_qkv(const short* __restrict__ Aq, const short* __restrict__ Ak,
                                                const short* __restrict__ Av,
                                                const short* __restrict__ Wq, const short* __restrict__ Wk,
                                                const short* __restrict__ Wv,
                                                const float* __restrict__ bq, const float* __restrict__ bk,
                                                const float* __restrict__ bv,
                                                short* __restrict__ Qh, short* __restrict__ Kh,
                                                short* __restrict__ Vt) {
  const int z = blockIdx.z;
  const short* A = z == 0 ? Aq : z == 1 ? Ak : Av;
  const short* W = z == 0 ? Wq : z == 1 ? Wk : Wv;
  const float* bias = z == 0 ? bq : z == 1 ? bk : bv;

  const int tid = threadIdx.x;
  const int wid = tid >> 6, lane = tid & 63;
  const int g = lane >> 4, li = lane & 15;
  const int wm = (wid >> 1) * 64, wn = (wid & 1) * 64;
  const int bn = blockIdx.x * 128, bm = blockIdx.y * 128;

  __shared__ __align__(16) short As[2][4096];
  __shared__ __align__(16) short Bs[2][4096];
  __shared__ __align__(16) short T2[64 * 136];  // V^T transpose staging

  auto stage = [&](int ks, int pb) {
    const int k0 = ks * 32;
#pragma unroll
    for (int i = 0; i < 2; ++i) {
      int slot = i * 256 + tid;
      int r = slot >> 2, pos = slot & 3;
      int lch = pos ^ ((r >> 1) & 3);
      gld16(A + (size_t)(bm + r) * DMODEL + k0 + lch * 8, As[pb] + slot * 8);
      gld16(W + (size_t)(bn + r) * DMODEL + k0 + lch * 8, Bs[pb] + slot * 8);
    }
  };

  f32x4 acc[4][4];
#pragma unroll
  for (int m = 0; m < 4; ++m)
#pragma unroll
    for (int n = 0; n < 4; ++n) acc[m][n] = (f32x4){0.f, 0.f, 0.f, 0.f};

  stage(0, 0);
  __syncthreads();
  for (int ks = 0; ks < 32; ++ks) {
    const int cur = ks & 1;
    if (ks + 1 < 32) stage(ks + 1, cur ^ 1);
    short8 av[4], bv4[4];
#pragma unroll
    for (int m = 0; m < 4; ++m) {
      int r = wm + m * 16 + li;
      av[m] = *(const short8*)(As[cur] + r * 32 + (g ^ ((r >> 1) & 3)) * 8);
    }
#pragma unroll
    for (int n = 0; n < 4; ++n) {
      int r = wn + n * 16 + li;
      bv4[n] = *(const short8*)(Bs[cur] + r * 32 + (g ^ ((r >> 1) & 3)) * 8);
    }
    __builtin_amdgcn_s_setprio(1);
#pragma unroll
    for (int m = 0; m < 4; ++m)
#pragma unroll
      for (int n = 0; n < 4; ++n) acc[m][n] = mfma_bf16(av[m], bv4[n], acc[m][n]);
    __builtin_amdgcn_s_setprio(0);
    __syncthreads();
  }

  if (z < 2) {
    short* out = z == 0 ? Qh : Kh;
#pragma unroll
    for (int n = 0; n < 4; ++n) {
      int col = bn + wn + n * 16 + li;
      float bb = bias[col];
      int h = col >> 6, dk = col & 63;
#pragma unroll
      for (int m = 0; m < 4; ++m)
#pragma unroll
        for (int j = 0; j < 4; ++j) {
          int row = bm + wm + m * 16 + g * 4 + j;
          int b_ = row >> 11, s_ = row & 2047;
          out[(size_t)((b_ * NH + h) * S_LEN + s_) * DKH + dk] = f2bf(acc[m][n][j] + bb);
        }
    }
  } else {  // V^T via two-pass LDS transpose, coalesced along s
    short* out = Vt;
    const int b_ = bm >> 11;
    const int sbase = bm & 2047;
#pragma unroll
    for (int ph = 0; ph < 2; ++ph) {
      __syncthreads();
      if ((wid & 1) == ph) {
#pragma unroll
        for (int n = 0; n < 4; ++n) {
          int colL = n * 16 + li;
          float bb = bias[bn + ph * 64 + colL];
#pragma unroll
          for (int m = 0; m < 4; ++m)
#pragma unroll
            for (int j = 0; j < 4; ++j) {
              int rowL = wm + m * 16 + g * 4 + j;
              T2[colL * 136 + rowL] = f2bf(acc[m][n][j] + bb);
            }
        }
      }
      __syncthreads();
      int dr = tid >> 2, qc = tid & 3;
      int nglob = bn + ph * 64 + dr;
      int h = nglob >> 6, dk = nglob & 63;
      short* op = out + (size_t)((b_ * NH + h) * DKH + dk) * S_LEN + sbase + qc * 32;
      const short* tp = T2 + dr * 136 + qc * 32;
#pragma unroll
      for (int i = 0; i < 4; ++i) *(short8*)(op + i * 8) = *(const short8*)(tp + i * 8);
    }
  }
}

// ---------------- output projection GEMM (double-buffered): fp32 out [M,N] ----------------
__global__ __launch_bounds__(256) void proj_out(const short* __restrict__ A, const short* __restrict__ W,
                                                const float* __restrict__ bias, float* __restrict__ out) {
  const int tid = threadIdx.x;
  const int wid = tid >> 6, lane = tid & 63;
  const int g = lane >> 4, li = lane & 15;
  const int wm = (wid >> 1) * 64, wn = (wid & 1) * 64;
  const int bn = blockIdx.x * 128, bm = blockIdx.y * 128;

  __shared__ __align__(16) short As[2][4096];
  __shared__ __align__(16) short Bs[2][4096];

  auto stage = [&](int ks, int pb) {
    const int k0 = ks * 32;
#pragma unroll
    for (int i = 0; i < 2; ++i) {
      int slot = i * 256 + tid;
      int r = slot >> 2, pos = slot & 3;
      int lch = pos ^ ((r >> 1) & 3);
      gld16(A + (size_t)(bm + r) * DMODEL + k0 + lch * 8, As[pb] + slot * 8);
      gld16(W + (size_t)(bn + r) * DMODEL + k0 + lch * 8, Bs[pb] + slot * 8);
    }
  };

  f32x4 acc[4][4];
#pragma unroll
  for (int m = 0; m < 4; ++m)
#pragma unroll
    for (int n = 0; n < 4; ++n) acc[m][n] = (f32x4){0.f, 0.f, 0.f, 0.f};

  stage(0, 0);
  __syncthreads();
  for (int ks = 0; ks < 32; ++ks) {
    const int cur = ks & 1;
    if (ks + 1 < 32) stage(ks + 1, cur ^ 1);
    short8 av[4], bv4[4];
#pragma unroll
    for (int m = 0; m < 4; ++m) {
      int r = wm + m * 16 + li;
      av[m] = *(const short8*)(As[cur] + r * 32 + (g ^ ((r >> 1) & 3)) * 8);
    }
#pragma unroll
    for (int n = 0; n < 4; ++n) {
      int r = wn + n * 16 + li;
      bv4[n] = *(const short8*)(Bs[cur] + r * 32 + (g ^ ((r >> 1) & 3)) * 8);
    }
    __builtin_amdgcn_s_setprio(1);
#pragma unroll
    for (int m = 0; m < 4; ++m)
#pragma unroll
      for (int n = 0; n < 4; ++n) acc[m][n] = mfma_bf16(av[m], bv4[n], acc[m][n]);
    __builtin_amdgcn_s_setprio(0);
    __syncthreads();
  }

#pragma unroll
  for (int n = 0; n < 4; ++n) {
    int col = bn + wn + n * 16 + li;
    float bb = bias[col];
#pragma unroll
    for (int m = 0; m < 4; ++m)
#pragma unroll
      for (int j = 0; j < 4; ++j) {
        int row = bm + wm + m * 16 + g * 4 + j;
        out[(size_t)row * DMODEL + col] = acc[m][n][j] + bb;
      }
  }
}

// ---------------- fused attention (R6 structure + NT p-stores + folded linv + stage2 overlap) ----------------
__global__ __launch_bounds__(256) void attn_fused(const short* __restrict__ Qh, const short* __restrict__ Kh,
                                                  const short* __restrict__ Vt,
                                                  const unsigned long long* __restrict__ maskb,
                                                  const unsigned* __restrict__ mall,
                                                  const float* __restrict__ maxKn,
                                                  float* __restrict__ pattn, short* __restrict__ xout) {
  const int tid = threadIdx.x;
  const int wid = tid >> 6, lane = tid & 63;
  const int g = lane >> 4, li = lane & 15;
  // XCD-chunked swizzle (1024 % 8 == 0, bijective)
  int swz = (blockIdx.x & 7) * 128 + (blockIdx.x >> 3);
  const int qblk = swz & 31;
  const int rest = swz >> 5;
  const int h = rest & 15, b = rest >> 4;
  const int bh = b * NH + h;
  const int q0 = qblk * 64 + wid * 16;

  const short* qptr = Qh + (size_t)(bh * S_LEN + q0 + li) * DKH;
  const short8 aq0 = *(const short8*)(qptr + g * 8);
  const short8 aq1 = *(const short8*)(qptr + 32 + g * 8);

  // ||q_row||^2 for row q0+li (exact values fed to MFMA)
  float qn2 = 0.f;
#pragma unroll
  for (int e = 0; e < 8; ++e) {
    float f0 = bf2f(aq0[e]), f1 = bf2f(aq1[e]);
    qn2 += f0 * f0 + f1 * f1;
  }
  qn2 += __shfl_xor(qn2, 16);
  qn2 += __shfl_xor(qn2, 32);
  const float mk = maxKn[bh];

  float M2[4], lsum[4], off[4];
  unsigned ms[4];
#pragma unroll
  for (int j = 0; j < 4; ++j) {
    float qn = __shfl(qn2, g * 4 + j);
    M2[j] = sqrtf(qn) * mk * SC + 1.0f;  // Cauchy-Schwarz upper bound, +1 margin
    lsum[j] = 0.f;
    ms[j] = mall[b * S_LEN + q0 + g * 4 + j];
  }

  // LDS union: sweep1 two 128x64 K bufs (0..16384); sweep2 dbuf K(0..8192)/V(8192..16384) + Ps(16384..20480)
  __shared__ __align__(16) short SB[20480];

  auto stage1 = [&](int t) {
    short* dst = SB + (t & 1) * 8192;
#pragma unroll
    for (int i = 0; i < 4; ++i) {
      int slot = i * 256 + tid;
      int r = slot >> 3, pos = slot & 7;
      int lch = pos ^ (r & 7);
      gld16(Kh + (size_t)(bh * S_LEN + t * 128 + r) * DKH + lch * 8, dst + slot * 8);
    }
  };
  auto stage2 = [&](int kt) {
    const int pb = kt & 1;
    short* Kd = SB + pb * 4096;
    short* Vd = SB + 8192 + pb * 4096;
    const int k0 = kt * 64;
#pragma unroll
    for (int i = 0; i < 2; ++i) {
      int slot = i * 256 + tid;
      int r = slot >> 3, pos = slot & 7;
      int lch = pos ^ (r & 7);
      gld16(Kh + (size_t)(bh * S_LEN + k0 + r) * DKH + lch * 8, Kd + slot * 8);
      gld16(Vt + (size_t)(bh * DKH + r) * S_LEN + k0 + lch * 8, Vd + slot * 8);
    }
  };

  // ---- sweep 1: l = sum exp2(s2 - M2), 128 k-rows per iter, double-buffered ----
  stage1(0);
  __syncthreads();
  for (int t = 0; t < 16; ++t) {
    const short* Kc = SB + (t & 1) * 8192;
    if (t + 1 < 16) stage1(t + 1);
#pragma unroll
    for (int half = 0; half < 2; ++half) {
      f32x4 acc[4];
      __builtin_amdgcn_s_setprio(1);
#pragma unroll
      for (int nf = 0; nf < 4; ++nf) {
        acc[nf] = (f32x4){0.f, 0.f, 0.f, 0.f};
        int rB = half * 64 + nf * 16 + li;
        const short8 b0 = *(const short8*)(Kc + rB * 64 + ((0 + g) ^ (rB & 7)) * 8);
        const short8 b1 = *(const short8*)(Kc + rB * 64 + ((4 + g) ^ (rB & 7)) * 8);
        acc[nf] = mfma_bf16(aq0, b0, acc[nf]);
        acc[nf] = mfma_bf16(aq1, b1, acc[nf]);
      }
      __builtin_amdgcn_s_setprio(0);
#pragma unroll
      for (int j = 0; j < 4; ++j) {
        float s0 = acc[0][j] * SC - M2[j];
        float s1 = acc[1][j] * SC - M2[j];
        float s2 = acc[2][j] * SC - M2[j];
        float s3 = acc[3][j] * SC - M2[j];
        if (!((ms[j] >> (t * 2 + half)) & 1)) {
          unsigned long long mb = maskb[(size_t)(b * S_LEN + q0 + g * 4 + j) * 32 + t * 2 + half];
          if (!((mb >> li) & 1)) s0 = -INFINITY;
          if (!((mb >> (16 + li)) & 1)) s1 = -INFINITY;
          if (!((mb >> (32 + li)) & 1)) s2 = -INFINITY;
          if (!((mb >> (48 + li)) & 1)) s3 = -INFINITY;
        }
        lsum[j] += e2(s0) + e2(s1) + e2(s2) + e2(s3);
      }
    }
    __syncthreads();
  }
  // overlap: first sweep-2 staging flies during the reduction (safe: after last barrier)
  stage2(0);
  // reduce l across the 16 li lanes
#pragma unroll
  for (int d = 1; d < 16; d <<= 1)
#pragma unroll
    for (int j = 0; j < 4; ++j) lsum[j] += __shfl_xor(lsum[j], d);
#pragma unroll
  for (int j = 0; j < 4; ++j) off[j] = M2[j] + __builtin_amdgcn_logf(lsum[j]);  // p = exp2(acc*SC - off)

  // ---- sweep 2: p write + PV, double-buffered, normalized P in Ps (R6-validated order) ----
  f32x4 accx[4];
#pragma unroll
  for (int nf = 0; nf < 4; ++nf) accx[nf] = (f32x4){0.f, 0.f, 0.f, 0.f};

  __syncthreads();
  for (int kt = 0; kt < 32; ++kt) {
    const int k0 = kt * 64;
    const int cur = kt & 1;
    const short* Kc = SB + cur * 4096;
    const short* Vc = SB + 8192 + cur * 4096;
    short* Ps = SB + 16384;
    if (kt + 1 < 32) stage2(kt + 1);

    f32x4 acc[4];
    __builtin_amdgcn_s_setprio(1);
#pragma unroll
    for (int nf = 0; nf < 4; ++nf) {
      acc[nf] = (f32x4){0.f, 0.f, 0.f, 0.f};
      int rB = nf * 16 + li;
      const short8 b0 = *(const short8*)(Kc + rB * 64 + ((0 + g) ^ (rB & 7)) * 8);
      const short8 b1 = *(const short8*)(Kc + rB * 64 + ((4 + g) ^ (rB & 7)) * 8);
      acc[nf] = mfma_bf16(aq0, b0, acc[nf]);
      acc[nf] = mfma_bf16(aq1, b1, acc[nf]);
    }
    __builtin_amdgcn_s_setprio(0);

    // softmax -> per-wave bf16 NORMALIZED p tile in LDS (swizzled); linv folded into exponent
#pragma unroll
    for (int j = 0; j < 4; ++j) {
      const int qrow = q0 + g * 4 + j;
      bool full = (ms[j] >> kt) & 1;
      unsigned long long mb = full ? ~0ull : maskb[(size_t)(b * S_LEN + qrow) * 32 + kt];
      const int row = g * 4 + j;
#pragma unroll
      for (int nf = 0; nf < 4; ++nf) {
        float s = acc[nf][j] * SC - off[j];
        if (!full && !((mb >> (nf * 16 + li)) & 1)) s = -INFINITY;
        float p = e2(s);
        int col = nf * 16 + li;
        int sidx = row * 64 + (((col >> 3) ^ (row & 7)) * 8) + (col & 7);
        Ps[wid * 1024 + sidx] = f2bf(p);
      }
    }

    // PV on normalized p
    const short8 pa0 = *(const short8*)(Ps + wid * 1024 + li * 64 + ((0 + g) ^ (li & 7)) * 8);
    const short8 pa1 = *(const short8*)(Ps + wid * 1024 + li * 64 + ((4 + g) ^ (li & 7)) * 8);
    __builtin_amdgcn_s_setprio(1);
#pragma unroll
    for (int nf = 0; nf < 4; ++nf) {
      int rv = nf * 16 + li;
      const short8 v0 = *(const short8*)(Vc + rv * 64 + ((0 + g) ^ (rv & 7)) * 8);
      const short8 v1 = *(const short8*)(Vc + rv * 64 + ((4 + g) ^ (rv & 7)) * 8);
      accx[nf] = mfma_bf16(pa0, v0, accx[nf]);
      accx[nf] = mfma_bf16(pa1, v1, accx[nf]);
    }
    __builtin_amdgcn_s_setprio(0);

    // cooperative vectorized p_attn write AFTER PV (R6-validated position); nontemporal
    {
      const int rg = lane >> 4;
      const int c = (lane & 15) * 4;
#pragma unroll
      for (int s = 0; s < 4; ++s) {
        int r = s * 4 + rg;
        int chunk = (c >> 3) ^ (r & 7);
        sv4 pv4 = *(const sv4*)(Ps + wid * 1024 + r * 64 + chunk * 8 + (c & 7));
        f32x4 w4;
        w4[0] = bf2f(pv4[0]);
        w4[1] = bf2f(pv4[1]);
        w4[2] = bf2f(pv4[2]);
        w4[3] = bf2f(pv4[3]);
        __builtin_nontemporal_store(w4, (f32x4*)(pattn + (size_t)(bh * S_LEN + q0 + r) * S_LEN + k0 + c));
      }
    }
    __syncthreads();
  }

#pragma unroll
  for (int nf = 0; nf < 4; ++nf) {
    int d = nf * 16 + li;
#pragma unroll
    for (int j = 0; j < 4; ++j) {
      int q = q0 + g * 4 + j;
      xout[(size_t)(b * S_LEN + q) * DMODEL + h * DKH + d] = f2bf(accx[nf][j]);
    }
  }
}

extern "C" void kernel_launch(void* const* d_in, const int* in_sizes, int n_in,
                              void* d_out, int out_size, void* d_ws, size_t ws_size,
                              hipStream_t stream) {
  (void)in_sizes; (void)n_in; (void)out_size; (void)ws_size;
  const float* query = (const float*)d_in[0];
  const float* key = (const float*)d_in[1];
  const float* value = (const float*)d_in[2];
  const int* mask = (const int*)d_in[3];
  const float* wq = (const float*)d_in[4];
  const float* bq = (const float*)d_in[5];
  const float* wk = (const float*)d_in[6];
  const float* bk = (const float*)d_in[7];
  const float* wv = (const float*)d_in[8];
  const float* bv = (const float*)d_in[9];
  const float* wo = (const float*)d_in[10];
  const float* bo = (const float*)d_in[11];

  char* ws = (char*)d_ws;
  const size_t MB = 1u << 20;
  short* qb = (short*)(ws + 0 * MB);
  short* kb = (short*)(ws + 8 * MB);
  short* vb = (short*)(ws + 16 * MB);
  short* wqT = (short*)(ws + 24 * MB);
  short* wkT = (short*)(ws + 26 * MB);
  short* wvT = (short*)(ws + 28 * MB);
  short* woT = (short*)(ws + 30 * MB);
  short* Qh = (short*)(ws + 32 * MB);
  short* Kh = (short*)(ws + 40 * MB);
  short* Vt = (short*)(ws + 48 * MB);
  float* maxKn = (float*)(ws + 56 * MB);
  unsigned* mall = (unsigned*)(ws + 56 * MB + 64 * 1024);
  short* xb = (short*)(ws + 57 * MB);
  // maskb aliases vb's region: maskpack launches after proj_qkv has consumed vb
  unsigned long long* maskb = (unsigned long long*)(ws + 16 * MB);

  float* out_x = (float*)d_out;
  float* out_p = (float*)d_out + 4194304;

  cast3_kernel<<<dim3(4096, 3), 256, 0, stream>>>(query, key, value, qb, kb, vb);
  wtrans_kernel<<<dim3(16, 16, 4), 256, 0, stream>>>(wq, wk, wv, wo, wqT, wkT, wvT, woT);
  proj_qkv<<<dim3(8, 32, 3), 256, 0, stream>>>(qb, kb, vb, wqT, wkT, wvT, bq, bk, bv, Qh, Kh, Vt);
  maskpack_kernel<<<dim3(4096), 256, 0, stream>>>(mask, maskb, mall);
  knorm_kernel<<<dim3(32), 256, 0, stream>>>(Kh, maxKn);
  attn_fused<<<dim3(1024), 256, 0, stream>>>(Qh, Kh, Vt, maskb, mall, maxKn, out_p, xb);
  proj_out<<<dim3(8, 32), 256, 0, stream>>>(xb, woT, bo, out_x);
}

// Round 12
// 265.658 us; speedup vs baseline: 1.6644x; 1.0585x over previous
//
#include <hip/hip_runtime.h>
#include <hip/hip_bf16.h>
#include <math.h>

typedef __attribute__((ext_vector_type(8))) short short8;
typedef __attribute__((ext_vector_type(4))) short sv4;
typedef __attribute__((ext_vector_type(4))) float f32x4;

#define S_LEN 2048
#define NH 16
#define DMODEL 1024
#define DKH 64
// log2(e)/8 : scores tracked in exp2-units so exp() is a single v_exp_f32
#define SC 0.18033688011112042f

static __device__ __forceinline__ short f2bf(float f) {
  unsigned u = __builtin_bit_cast(unsigned, f);
  unsigned r = (u + 0x7fffu + ((u >> 16) & 1u)) >> 16;
  return (short)r;
}

static __device__ __forceinline__ float bf2f(short s) {
  return __builtin_bit_cast(float, ((unsigned)(unsigned short)s) << 16);
}

static __device__ __forceinline__ float e2(float x) { return __builtin_amdgcn_exp2f(x); }

static __device__ __forceinline__ void gld16(const void* g, void* l) {
  __builtin_amdgcn_global_load_lds((const __attribute__((address_space(1))) void*)g,
                                   (__attribute__((address_space(3))) void*)l, 16, 0, 0);
}

static __device__ __forceinline__ f32x4 mfma_bf16(short8 a, short8 b, f32x4 c) {
  return __builtin_amdgcn_mfma_f32_16x16x32_bf16(a, b, c, 0, 0, 0);
}

// ---------------- cast fp32 -> bf16 for q/k/v inputs ----------------
__global__ __launch_bounds__(256) void cast3_kernel(const float* __restrict__ q, const float* __restrict__ k,
                                                    const float* __restrict__ v,
                                                    short* __restrict__ oq, short* __restrict__ ok_,
                                                    short* __restrict__ ov) {
  const float* in = blockIdx.y == 0 ? q : (blockIdx.y == 1 ? k : v);
  short* out = blockIdx.y == 0 ? oq : (blockIdx.y == 1 ? ok_ : ov);
  int i = blockIdx.x * 256 + threadIdx.x;
  float4 f = ((const float4*)in)[i];
  sv4 o = {f2bf(f.x), f2bf(f.y), f2bf(f.z), f2bf(f.w)};
  ((sv4*)out)[i] = o;
}

// ---------------- bit-pack mask rows + all-ones summary ----------------
__global__ __launch_bounds__(256) void maskpack_kernel(const int* __restrict__ mask,
                                                       unsigned long long* __restrict__ mb,
                                                       unsigned* __restrict__ mall) {
  int row = blockIdx.x;  // b*S + q
  int w = threadIdx.x >> 6, lane = threadIdx.x & 63;
  const int* mp = mask + (size_t)row * S_LEN;
  __shared__ unsigned flags;
  if (threadIdx.x == 0) flags = 0;
  __syncthreads();
#pragma unroll
  for (int c = 0; c < 8; ++c) {
    int ci = w * 8 + c;
    unsigned long long bits = __ballot(mp[ci * 64 + lane] != 0);
    if (lane == 0) {
      mb[(size_t)row * 32 + ci] = bits;
      if (bits == ~0ull) atomicOr(&flags, 1u << ci);
    }
  }
  __syncthreads();
  if (threadIdx.x == 0) mall[row] = flags;
}

// ---------------- transpose-cast weights: out[n][k] = bf16(in[k][n]); also zero maxKn2 ----------------
__global__ __launch_bounds__(256) void wtrans_kernel(const float* __restrict__ w0, const float* __restrict__ w1,
                                                     const float* __restrict__ w2, const float* __restrict__ w3,
                                                     short* __restrict__ o0, short* __restrict__ o1,
                                                     short* __restrict__ o2, short* __restrict__ o3,
                                                     unsigned* __restrict__ maxKn2) {
  if (blockIdx.x == 0 && blockIdx.y == 0 && blockIdx.z == 0 && threadIdx.x < 32)
    maxKn2[threadIdx.x] = 0u;
  const float* in = blockIdx.z == 0 ? w0 : blockIdx.z == 1 ? w1 : blockIdx.z == 2 ? w2 : w3;
  short* out = blockIdx.z == 0 ? o0 : blockIdx.z == 1 ? o1 : blockIdx.z == 2 ? o2 : o3;
  __shared__ float t[64][65];
  int tx = threadIdx.x & 63, ty = threadIdx.x >> 6;
  int bx = blockIdx.x * 64, by = blockIdx.y * 64;  // bx: n, by: k
#pragma unroll
  for (int i = 0; i < 16; ++i)
    t[ty + i * 4][tx] = in[(by + ty + i * 4) * DMODEL + bx + tx];
  __syncthreads();
#pragma unroll
  for (int i = 0; i < 16; ++i)
    out[(bx + ty + i * 4) * DMODEL + by + tx] = f2bf(t[tx][ty + i * 4]);
}

// ---------------- batched Q/K/V projection GEMM (double-buffered) ----------------
// z=0 (Q), z=1 (K): out bf16 [B,H,S,DK].  z=2 (V): out bf16 [B,H,DK,S] (V^T).
// z=1 additionally accumulates per-(b,h) max row-norm^2 into maxKn2 (uint-bits atomicMax).
__global__ __launch_bounds__(256) void proj_qkv(const short* __restrict__ Aq, const short* __restrict__ Ak,
                                                const short* __restrict__ Av,
                                                const short* __restrict__ Wq, const short* __restrict__ Wk,
                                                const short* __restrict__ Wv,
                                                const float* __restrict__ bq, const float* __restrict__ bk,
                                                const float* __restrict__ bv,
                                                short* __restrict__ Qh, short* __restrict__ Kh,
                                                short* __restrict__ Vt,
                                                unsigned* __restrict__ maxKn2) {
  const int z = blockIdx.z;
  const short* A = z == 0 ? Aq : z == 1 ? Ak : Av;
  const short* W = z == 0 ? Wq : z == 1 ? Wk : Wv;
  const float* bias = z == 0 ? bq : z == 1 ? bk : bv;

  const int tid = threadIdx.x;
  const int wid = tid >> 6, lane = tid & 63;
  const int g = lane >> 4, li = lane & 15;
  const int wm = (wid >> 1) * 64, wn = (wid & 1) * 64;
  const int bn = blockIdx.x * 128, bm = blockIdx.y * 128;

  __shared__ __align__(16) short As[2][4096];
  __shared__ __align__(16) short Bs[2][4096];
  __shared__ __align__(16) short T2[64 * 136];  // V^T transpose staging

  auto stage = [&](int ks, int pb) {
    const int k0 = ks * 32;
#pragma unroll
    for (int i = 0; i < 2; ++i) {
      int slot = i * 256 + tid;
      int r = slot >> 2, pos = slot & 3;
      int lch = pos ^ ((r >> 1) & 3);
      gld16(A + (size_t)(bm + r) * DMODEL + k0 + lch * 8, As[pb] + slot * 8);
      gld16(W + (size_t)(bn + r) * DMODEL + k0 + lch * 8, Bs[pb] + slot * 8);
    }
  };

  f32x4 acc[4][4];
#pragma unroll
  for (int m = 0; m < 4; ++m)
#pragma unroll
    for (int n = 0; n < 4; ++n) acc[m][n] = (f32x4){0.f, 0.f, 0.f, 0.f};

  stage(0, 0);
  __syncthreads();
  for (int ks = 0; ks < 32; ++ks) {
    const int cur = ks & 1;
    if (ks + 1 < 32) stage(ks + 1, cur ^ 1);
    short8 av[4], bv4[4];
#pragma unroll
    for (int m = 0; m < 4; ++m) {
      int r = wm + m * 16 + li;
      av[m] = *(const short8*)(As[cur] + r * 32 + (g ^ ((r >> 1) & 3)) * 8);
    }
#pragma unroll
    for (int n = 0; n < 4; ++n) {
      int r = wn + n * 16 + li;
      bv4[n] = *(const short8*)(Bs[cur] + r * 32 + (g ^ ((r >> 1) & 3)) * 8);
    }
    __builtin_amdgcn_s_setprio(1);
#pragma unroll
    for (int m = 0; m < 4; ++m)
#pragma unroll
      for (int n = 0; n < 4; ++n) acc[m][n] = mfma_bf16(av[m], bv4[n], acc[m][n]);
    __builtin_amdgcn_s_setprio(0);
    __syncthreads();
  }

  if (z < 2) {
    short* out = z == 0 ? Qh : Kh;
#pragma unroll
    for (int n = 0; n < 4; ++n) {
      int col = bn + wn + n * 16 + li;
      float bb = bias[col];
      int h = col >> 6, dk = col & 63;
#pragma unroll
      for (int m = 0; m < 4; ++m)
#pragma unroll
        for (int j = 0; j < 4; ++j) {
          int row = bm + wm + m * 16 + g * 4 + j;
          int b_ = row >> 11, s_ = row & 2047;
          out[(size_t)((b_ * NH + h) * S_LEN + s_) * DKH + dk] = f2bf(acc[m][n][j] + bb);
        }
    }
    if (z == 1) {
      // fused knorm: this wave covers full 64-col head (bn+wn)>>6 for rows wm..wm+63
      float sn[4][4];
#pragma unroll
      for (int m = 0; m < 4; ++m)
#pragma unroll
        for (int j = 0; j < 4; ++j) {
          float s = 0.f;
#pragma unroll
          for (int n = 0; n < 4; ++n) {
            float v = acc[m][n][j] + bias[bn + wn + n * 16 + li];
            s += v * v;
          }
          sn[m][j] = s;
        }
      // sum across the 16 li lanes -> full 64-col row norms
#pragma unroll
      for (int d = 1; d < 16; d <<= 1)
#pragma unroll
        for (int m = 0; m < 4; ++m)
#pragma unroll
          for (int j = 0; j < 4; ++j) sn[m][j] += __shfl_xor(sn[m][j], d);
      float mx = 0.f;
#pragma unroll
      for (int m = 0; m < 4; ++m)
#pragma unroll
        for (int j = 0; j < 4; ++j) mx = fmaxf(mx, sn[m][j]);
      mx = fmaxf(mx, __shfl_xor(mx, 16));
      mx = fmaxf(mx, __shfl_xor(mx, 32));
      if (lane == 0) {
        int head = (bn + wn) >> 6;
        int b_ = bm >> 11;
        atomicMax(&maxKn2[b_ * NH + head], __builtin_bit_cast(unsigned, mx));
      }
    }
  } else {  // V^T via two-pass LDS transpose, coalesced along s
    short* out = Vt;
    const int b_ = bm >> 11;
    const int sbase = bm & 2047;
#pragma unroll
    for (int ph = 0; ph < 2; ++ph) {
      __syncthreads();
      if ((wid & 1) == ph) {
#pragma unroll
        for (int n = 0; n < 4; ++n) {
          int colL = n * 16 + li;
          float bb = bias[bn + ph * 64 + colL];
#pragma unroll
          for (int m = 0; m < 4; ++m)
#pragma unroll
            for (int j = 0; j < 4; ++j) {
              int rowL = wm + m * 16 + g * 4 + j;
              T2[colL * 136 + rowL] = f2bf(acc[m][n][j] + bb);
            }
        }
      }
      __syncthreads();
      int dr = tid >> 2, qc = tid & 3;
      int nglob = bn + ph * 64 + dr;
      int h = nglob >> 6, dk = nglob & 63;
      short* op = out + (size_t)((b_ * NH + h) * DKH + dk) * S_LEN + sbase + qc * 32;
      const short* tp = T2 + dr * 136 + qc * 32;
#pragma unroll
      for (int i = 0; i < 4; ++i) *(short8*)(op + i * 8) = *(const short8*)(tp + i * 8);
    }
  }
}

// ---------------- output projection GEMM (double-buffered, 128x64 tile, 512 blocks): fp32 out ----------------
__global__ __launch_bounds__(256) void proj_out(const short* __restrict__ A, const short* __restrict__ W,
                                                const float* __restrict__ bias, float* __restrict__ out) {
  const int tid = threadIdx.x;
  const int wid = tid >> 6, lane = tid & 63;
  const int g = lane >> 4, li = lane & 15;
  const int wm = (wid >> 1) * 64, wn = (wid & 1) * 32;
  const int bn = blockIdx.x * 64, bm = blockIdx.y * 128;

  __shared__ __align__(16) short As[2][4096];
  __shared__ __align__(16) short Bs[2][2048];

  auto stage = [&](int ks, int pb) {
    const int k0 = ks * 32;
#pragma unroll
    for (int i = 0; i < 2; ++i) {
      int slot = i * 256 + tid;
      int r = slot >> 2, pos = slot & 3;
      int lch = pos ^ ((r >> 1) & 3);
      gld16(A + (size_t)(bm + r) * DMODEL + k0 + lch * 8, As[pb] + slot * 8);
    }
    {
      int slot = tid;
      int r = slot >> 2, pos = slot & 3;
      int lch = pos ^ ((r >> 1) & 3);
      gld16(W + (size_t)(bn + r) * DMODEL + k0 + lch * 8, Bs[pb] + slot * 8);
    }
  };

  f32x4 acc[4][2];
#pragma unroll
  for (int m = 0; m < 4; ++m)
#pragma unroll
    for (int n = 0; n < 2; ++n) acc[m][n] = (f32x4){0.f, 0.f, 0.f, 0.f};

  stage(0, 0);
  __syncthreads();
  for (int ks = 0; ks < 32; ++ks) {
    const int cur = ks & 1;
    if (ks + 1 < 32) stage(ks + 1, cur ^ 1);
    short8 av[4], bv4[2];
#pragma unroll
    for (int m = 0; m < 4; ++m) {
      int r = wm + m * 16 + li;
      av[m] = *(const short8*)(As[cur] + r * 32 + (g ^ ((r >> 1) & 3)) * 8);
    }
#pragma unroll
    for (int n = 0; n < 2; ++n) {
      int r = wn + n * 16 + li;
      bv4[n] = *(const short8*)(Bs[cur] + r * 32 + (g ^ ((r >> 1) & 3)) * 8);
    }
    __builtin_amdgcn_s_setprio(1);
#pragma unroll
    for (int m = 0; m < 4; ++m)
#pragma unroll
      for (int n = 0; n < 2; ++n) acc[m][n] = mfma_bf16(av[m], bv4[n], acc[m][n]);
    __builtin_amdgcn_s_setprio(0);
    __syncthreads();
  }

#pragma unroll
  for (int n = 0; n < 2; ++n) {
    int col = bn + wn + n * 16 + li;
    float bb = bias[col];
#pragma unroll
    for (int m = 0; m < 4; ++m)
#pragma unroll
      for (int j = 0; j < 4; ++j) {
        int row = bm + wm + m * 16 + g * 4 + j;
        out[(size_t)row * DMODEL + col] = acc[m][n][j] + bb;
      }
  }
}

// ---------------- fused attention (R11-validated) ----------------
__global__ __launch_bounds__(256) void attn_fused(const short* __restrict__ Qh, const short* __restrict__ Kh,
                                                  const short* __restrict__ Vt,
                                                  const unsigned long long* __restrict__ maskb,
                                                  const unsigned* __restrict__ mall,
                                                  const unsigned* __restrict__ maxKn2,
                                                  float* __restrict__ pattn, short* __restrict__ xout) {
  const int tid = threadIdx.x;
  const int wid = tid >> 6, lane = tid & 63;
  const int g = lane >> 4, li = lane & 15;
  // XCD-chunked swizzle (1024 % 8 == 0, bijective)
  int swz = (blockIdx.x & 7) * 128 + (blockIdx.x >> 3);
  const int qblk = swz & 31;
  const int rest = swz >> 5;
  const int h = rest & 15, b = rest >> 4;
  const int bh = b * NH + h;
  const int q0 = qblk * 64 + wid * 16;

  const short* qptr = Qh + (size_t)(bh * S_LEN + q0 + li) * DKH;
  const short8 aq0 = *(const short8*)(qptr + g * 8);
  const short8 aq1 = *(const short8*)(qptr + 32 + g * 8);

  // ||q_row||^2 for row q0+li (exact values fed to MFMA)
  float qn2 = 0.f;
#pragma unroll
  for (int e = 0; e < 8; ++e) {
    float f0 = bf2f(aq0[e]), f1 = bf2f(aq1[e]);
    qn2 += f0 * f0 + f1 * f1;
  }
  qn2 += __shfl_xor(qn2, 16);
  qn2 += __shfl_xor(qn2, 32);
  const float mk = sqrtf(__builtin_bit_cast(float, maxKn2[bh]));

  float M2[4], lsum[4], off[4];
  unsigned ms[4];
#pragma unroll
  for (int j = 0; j < 4; ++j) {
    float qn = __shfl(qn2, g * 4 + j);
    M2[j] = sqrtf(qn) * mk * SC + 1.0f;  // Cauchy-Schwarz upper bound, +1 margin
    lsum[j] = 0.f;
    ms[j] = mall[b * S_LEN + q0 + g * 4 + j];
  }

  // LDS union: sweep1 two 128x64 K bufs (0..16384); sweep2 dbuf K(0..8192)/V(8192..16384) + Ps(16384..20480)
  __shared__ __align__(16) short SB[20480];

  auto stage1 = [&](int t) {
    short* dst = SB + (t & 1) * 8192;
#pragma unroll
    for (int i = 0; i < 4; ++i) {
      int slot = i * 256 + tid;
      int r = slot >> 3, pos = slot & 7;
      int lch = pos ^ (r & 7);
      gld16(Kh + (size_t)(bh * S_LEN + t * 128 + r) * DKH + lch * 8, dst + slot * 8);
    }
  };
  auto stage2 = [&](int kt) {
    const int pb = kt & 1;
    short* Kd = SB + pb * 4096;
    short* Vd = SB + 8192 + pb * 4096;
    const int k0 = kt * 64;
#pragma unroll
    for (int i = 0; i < 2; ++i) {
      int slot = i * 256 + tid;
      int r = slot >> 3, pos = slot & 7;
      int lch = pos ^ (r & 7);
      gld16(Kh + (size_t)(bh * S_LEN + k0 + r) * DKH + lch * 8, Kd + slot * 8);
      gld16(Vt + (size_t)(bh * DKH + r) * S_LEN + k0 + lch * 8, Vd + slot * 8);
    }
  };

  // ---- sweep 1: l = sum exp2(s2 - M2), 128 k-rows per iter, double-buffered ----
  stage1(0);
  __syncthreads();
  for (int t = 0; t < 16; ++t) {
    const short* Kc = SB + (t & 1) * 8192;
    if (t + 1 < 16) stage1(t + 1);
#pragma unroll
    for (int half = 0; half < 2; ++half) {
      f32x4 acc[4];
      __builtin_amdgcn_s_setprio(1);
#pragma unroll
      for (int nf = 0; nf < 4; ++nf) {
        acc[nf] = (f32x4){0.f, 0.f, 0.f, 0.f};
        int rB = half * 64 + nf * 16 + li;
        const short8 b0 = *(const short8*)(Kc + rB * 64 + ((0 + g) ^ (rB & 7)) * 8);
        const short8 b1 = *(const short8*)(Kc + rB * 64 + ((4 + g) ^ (rB & 7)) * 8);
        acc[nf] = mfma_bf16(aq0, b0, acc[nf]);
        acc[nf] = mfma_bf16(aq1, b1, acc[nf]);
      }
      __builtin_amdgcn_s_setprio(0);
#pragma unroll
      for (int j = 0; j < 4; ++j) {
        float s0 = acc[0][j] * SC - M2[j];
        float s1 = acc[1][j] * SC - M2[j];
        float s2 = acc[2][j] * SC - M2[j];
        float s3 = acc[3][j] * SC - M2[j];
        if (!((ms[j] >> (t * 2 + half)) & 1)) {
          unsigned long long mb = maskb[(size_t)(b * S_LEN + q0 + g * 4 + j) * 32 + t * 2 + half];
          if (!((mb >> li) & 1)) s0 = -INFINITY;
          if (!((mb >> (16 + li)) & 1)) s1 = -INFINITY;
          if (!((mb >> (32 + li)) & 1)) s2 = -INFINITY;
          if (!((mb >> (48 + li)) & 1)) s3 = -INFINITY;
        }
        lsum[j] += e2(s0) + e2(s1) + e2(s2) + e2(s3);
      }
    }
    __syncthreads();
  }
  // overlap: first sweep-2 staging flies during the reduction (safe: after last barrier)
  stage2(0);
  // reduce l across the 16 li lanes
#pragma unroll
  for (int d = 1; d < 16; d <<= 1)
#pragma unroll
    for (int j = 0; j < 4; ++j) lsum[j] += __shfl_xor(lsum[j], d);
#pragma unroll
  for (int j = 0; j < 4; ++j) off[j] = M2[j] + __builtin_amdgcn_logf(lsum[j]);  // p = exp2(acc*SC - off)

  // ---- sweep 2: p write + PV, double-buffered, normalized P in Ps (R6-validated order) ----
  f32x4 accx[4];
#pragma unroll
  for (int nf = 0; nf < 4; ++nf) accx[nf] = (f32x4){0.f, 0.f, 0.f, 0.f};

  __syncthreads();
  for (int kt = 0; kt < 32; ++kt) {
    const int k0 = kt * 64;
    const int cur = kt & 1;
    const short* Kc = SB + cur * 4096;
    const short* Vc = SB + 8192 + cur * 4096;
    short* Ps = SB + 16384;
    if (kt + 1 < 32) stage2(kt + 1);

    f32x4 acc[4];
    __builtin_amdgcn_s_setprio(1);
#pragma unroll
    for (int nf = 0; nf < 4; ++nf) {
      acc[nf] = (f32x4){0.f, 0.f, 0.f, 0.f};
      int rB = nf * 16 + li;
      const short8 b0 = *(const short8*)(Kc + rB * 64 + ((0 + g) ^ (rB & 7)) * 8);
      const short8 b1 = *(const short8*)(Kc + rB * 64 + ((4 + g) ^ (rB & 7)) * 8);
      acc[nf] = mfma_bf16(aq0, b0, acc[nf]);
      acc[nf] = mfma_bf16(aq1, b1, acc[nf]);
    }
    __builtin_amdgcn_s_setprio(0);

    // softmax -> per-wave bf16 NORMALIZED p tile in LDS (swizzled); linv folded into exponent
#pragma unroll
    for (int j = 0; j < 4; ++j) {
      const int qrow = q0 + g * 4 + j;
      bool full = (ms[j] >> kt) & 1;
      unsigned long long mb = full ? ~0ull : maskb[(size_t)(b * S_LEN + qrow) * 32 + kt];
      const int row = g * 4 + j;
#pragma unroll
      for (int nf = 0; nf < 4; ++nf) {
        float s = acc[nf][j] * SC - off[j];
        if (!full && !((mb >> (nf * 16 + li)) & 1)) s = -INFINITY;
        float p = e2(s);
        int col = nf * 16 + li;
        int sidx = row * 64 + (((col >> 3) ^ (row & 7)) * 8) + (col & 7);
        Ps[wid * 1024 + sidx] = f2bf(p);
      }
    }

    // PV on normalized p
    const short8 pa0 = *(const short8*)(Ps + wid * 1024 + li * 64 + ((0 + g) ^ (li & 7)) * 8);
    const short8 pa1 = *(const short8*)(Ps + wid * 1024 + li * 64 + ((4 + g) ^ (li & 7)) * 8);
    __builtin_amdgcn_s_setprio(1);
#pragma unroll
    for (int nf = 0; nf < 4; ++nf) {
      int rv = nf * 16 + li;
      const short8 v0 = *(const short8*)(Vc + rv * 64 + ((0 + g) ^ (rv & 7)) * 8);
      const short8 v1 = *(const short8*)(Vc + rv * 64 + ((4 + g) ^ (rv & 7)) * 8);
      accx[nf] = mfma_bf16(pa0, v0, accx[nf]);
      accx[nf] = mfma_bf16(pa1, v1, accx[nf]);
    }
    __builtin_amdgcn_s_setprio(0);

    // cooperative vectorized p_attn write AFTER PV (R6-validated position); nontemporal
    {
      const int rg = lane >> 4;
      const int c = (lane & 15) * 4;
#pragma unroll
      for (int s = 0; s < 4; ++s) {
        int r = s * 4 + rg;
        int chunk = (c >> 3) ^ (r & 7);
        sv4 pv4 = *(const sv4*)(Ps + wid * 1024 + r * 64 + chunk * 8 + (c & 7));
        f32x4 w4;
        w4[0] = bf2f(pv4[0]);
        w4[1] = bf2f(pv4[1]);
        w4[2] = bf2f(pv4[2]);
        w4[3] = bf2f(pv4[3]);
        __builtin_nontemporal_store(w4, (f32x4*)(pattn + (size_t)(bh * S_LEN + q0 + r) * S_LEN + k0 + c));
      }
    }
    __syncthreads();
  }

#pragma unroll
  for (int nf = 0; nf < 4; ++nf) {
    int d = nf * 16 + li;
#pragma unroll
    for (int j = 0; j < 4; ++j) {
      int q = q0 + g * 4 + j;
      xout[(size_t)(b * S_LEN + q) * DMODEL + h * DKH + d] = f2bf(accx[nf][j]);
    }
  }
}

extern "C" void kernel_launch(void* const* d_in, const int* in_sizes, int n_in,
                              void* d_out, int out_size, void* d_ws, size_t ws_size,
                              hipStream_t stream) {
  (void)in_sizes; (void)n_in; (void)out_size; (void)ws_size;
  const float* query = (const float*)d_in[0];
  const float* key = (const float*)d_in[1];
  const float* value = (const float*)d_in[2];
  const int* mask = (const int*)d_in[3];
  const float* wq = (const float*)d_in[4];
  const float* bq = (const float*)d_in[5];
  const float* wk = (const float*)d_in[6];
  const float* bk = (const float*)d_in[7];
  const float* wv = (const float*)d_in[8];
  const float* bv = (const float*)d_in[9];
  const float* wo = (const float*)d_in[10];
  const float* bo = (const float*)d_in[11];

  char* ws = (char*)d_ws;
  const size_t MB = 1u << 20;
  short* qb = (short*)(ws + 0 * MB);
  short* kb = (short*)(ws + 8 * MB);
  short* vb = (short*)(ws + 16 * MB);
  short* wqT = (short*)(ws + 24 * MB);
  short* wkT = (short*)(ws + 26 * MB);
  short* wvT = (short*)(ws + 28 * MB);
  short* woT = (short*)(ws + 30 * MB);
  short* Qh = (short*)(ws + 32 * MB);
  short* Kh = (short*)(ws + 40 * MB);
  short* Vt = (short*)(ws + 48 * MB);
  unsigned* maxKn2 = (unsigned*)(ws + 56 * MB);
  unsigned* mall = (unsigned*)(ws + 56 * MB + 64 * 1024);
  short* xb = (short*)(ws + 57 * MB);
  // maskb aliases vb's region: maskpack launches after proj_qkv has consumed vb
  unsigned long long* maskb = (unsigned long long*)(ws + 16 * MB);

  float* out_x = (float*)d_out;
  float* out_p = (float*)d_out + 4194304;

  cast3_kernel<<<dim3(4096, 3), 256, 0, stream>>>(query, key, value, qb, kb, vb);
  wtrans_kernel<<<dim3(16, 16, 4), 256, 0, stream>>>(wq, wk, wv, wo, wqT, wkT, wvT, woT, maxKn2);
  proj_qkv<<<dim3(8, 32, 3), 256, 0, stream>>>(qb, kb, vb, wqT, wkT, wvT, bq, bk, bv, Qh, Kh, Vt, maxKn2);
  maskpack_kernel<<<dim3(4096), 256, 0, stream>>>(mask, maskb, mall);
  attn_fused<<<dim3(1024), 256, 0, stream>>>(Qh, Kh, Vt, maskb, mall, maxKn2, out_p, xb);
  proj_out<<<dim3(16, 32), 256, 0, stream>>>(xb, woT, bo, out_x);
}

// Round 13
// 263.871 us; speedup vs baseline: 1.6757x; 1.0068x over previous
//
#include <hip/hip_runtime.h>
#include <hip/hip_bf16.h>
#include <math.h>

typedef __attribute__((ext_vector_type(8))) short short8;
typedef __attribute__((ext_vector_type(4))) short sv4;
typedef __attribute__((ext_vector_type(4))) float f32x4;

#define S_LEN 2048
#define NH 16
#define DMODEL 1024
#define DKH 64
// log2(e)/8 : scores tracked in exp2-units so exp() is a single v_exp_f32
#define SC 0.18033688011112042f

static __device__ __forceinline__ short f2bf(float f) {
  unsigned u = __builtin_bit_cast(unsigned, f);
  unsigned r = (u + 0x7fffu + ((u >> 16) & 1u)) >> 16;
  return (short)r;
}

static __device__ __forceinline__ float bf2f(short s) {
  return __builtin_bit_cast(float, ((unsigned)(unsigned short)s) << 16);
}

static __device__ __forceinline__ float e2(float x) { return __builtin_amdgcn_exp2f(x); }

static __device__ __forceinline__ void gld16(const void* g, void* l) {
  __builtin_amdgcn_global_load_lds((const __attribute__((address_space(1))) void*)g,
                                   (__attribute__((address_space(3))) void*)l, 16, 0, 0);
}

static __device__ __forceinline__ f32x4 mfma_bf16(short8 a, short8 b, f32x4 c) {
  return __builtin_amdgcn_mfma_f32_16x16x32_bf16(a, b, c, 0, 0, 0);
}

// ---------------- merged prep: cast3 (blocks 0..12287) + wtrans (12288..13311) + maskpack (13312..17407) ----------------
__global__ __launch_bounds__(256) void prep_kernel(const float* __restrict__ q, const float* __restrict__ k,
                                                   const float* __restrict__ v, const int* __restrict__ mask,
                                                   const float* __restrict__ w0, const float* __restrict__ w1,
                                                   const float* __restrict__ w2, const float* __restrict__ w3,
                                                   short* __restrict__ oq, short* __restrict__ ok_,
                                                   short* __restrict__ ov,
                                                   short* __restrict__ o0, short* __restrict__ o1,
                                                   short* __restrict__ o2, short* __restrict__ o3,
                                                   unsigned long long* __restrict__ mb,
                                                   unsigned* __restrict__ mall,
                                                   unsigned* __restrict__ maxKn2) {
  const int bid = blockIdx.x;
  const int tid = threadIdx.x;
  __shared__ float t[64][65];

  if (bid < 12288) {
    // ---- cast fp32 -> bf16 for q/k/v ----
    int y = bid / 4096, x = bid % 4096;
    const float* in = y == 0 ? q : (y == 1 ? k : v);
    short* out = y == 0 ? oq : (y == 1 ? ok_ : ov);
    int i = x * 256 + tid;
    float4 f = ((const float4*)in)[i];
    sv4 o = {f2bf(f.x), f2bf(f.y), f2bf(f.z), f2bf(f.w)};
    ((sv4*)out)[i] = o;
  } else if (bid < 13312) {
    // ---- transpose-cast weights ----
    int idx = bid - 12288;
    if (idx == 0 && tid < 32) maxKn2[tid] = 0u;
    int z = idx >> 8, rem = idx & 255;
    const float* in = z == 0 ? w0 : z == 1 ? w1 : z == 2 ? w2 : w3;
    short* out = z == 0 ? o0 : z == 1 ? o1 : z == 2 ? o2 : o3;
    int tx = tid & 63, ty = tid >> 6;
    int bx = (rem & 15) * 64, by = (rem >> 4) * 64;  // bx: n, by: k
#pragma unroll
    for (int i = 0; i < 16; ++i)
      t[ty + i * 4][tx] = in[(by + ty + i * 4) * DMODEL + bx + tx];
    __syncthreads();
#pragma unroll
    for (int i = 0; i < 16; ++i)
      out[(bx + ty + i * 4) * DMODEL + by + tx] = f2bf(t[tx][ty + i * 4]);
  } else {
    // ---- bit-pack mask rows + all-ones summary ----
    int row = bid - 13312;  // b*S + q
    int w = tid >> 6, lane = tid & 63;
    const int* mp = mask + (size_t)row * S_LEN;
    unsigned* flags = (unsigned*)&t[0][0];
    if (tid == 0) *flags = 0;
    __syncthreads();
#pragma unroll
    for (int c = 0; c < 8; ++c) {
      int ci = w * 8 + c;
      unsigned long long bits = __ballot(mp[ci * 64 + lane] != 0);
      if (lane == 0) {
        mb[(size_t)row * 32 + ci] = bits;
        if (bits == ~0ull) atomicOr(flags, 1u << ci);
      }
    }
    __syncthreads();
    if (tid == 0) mall[row] = *flags;
  }
}

// ---------------- batched Q/K/V projection GEMM (double-buffered) ----------------
// z=0 (Q), z=1 (K): out bf16 [B,H,S,DK].  z=2 (V): out bf16 [B,H,DK,S] (V^T).
// z=1 additionally accumulates per-(b,h) max row-norm^2 into maxKn2 (uint-bits atomicMax).
__global__ __launch_bounds__(256) void proj_qkv(const short* __restrict__ Aq, const short* __restrict__ Ak,
                                                const short* __restrict__ Av,
                                                const short* __restrict__ Wq, const short* __restrict__ Wk,
                                                const short* __restrict__ Wv,
                                                const float* __restrict__ bq, const float* __restrict__ bk,
                                                const float* __restrict__ bv,
                                                short* __restrict__ Qh, short* __restrict__ Kh,
                                                short* __restrict__ Vt,
                                                unsigned* __restrict__ maxKn2) {
  const int z = blockIdx.z;
  const short* A = z == 0 ? Aq : z == 1 ? Ak : Av;
  const short* W = z == 0 ? Wq : z == 1 ? Wk : Wv;
  const float* bias = z == 0 ? bq : z == 1 ? bk : bv;

  const int tid = threadIdx.x;
  const int wid = tid >> 6, lane = tid & 63;
  const int g = lane >> 4, li = lane & 15;
  const int wm = (wid >> 1) * 64, wn = (wid & 1) * 64;
  const int bn = blockIdx.x * 128, bm = blockIdx.y * 128;

  __shared__ __align__(16) short As[2][4096];
  __shared__ __align__(16) short Bs[2][4096];
  __shared__ __align__(16) short T2[64 * 136];  // V^T transpose staging

  auto stage = [&](int ks, int pb) {
    const int k0 = ks * 32;
#pragma unroll
    for (int i = 0; i < 2; ++i) {
      int slot = i * 256 + tid;
      int r = slot >> 2, pos = slot & 3;
      int lch = pos ^ ((r >> 1) & 3);
      gld16(A + (size_t)(bm + r) * DMODEL + k0 + lch * 8, As[pb] + slot * 8);
      gld16(W + (size_t)(bn + r) * DMODEL + k0 + lch * 8, Bs[pb] + slot * 8);
    }
  };

  f32x4 acc[4][4];
#pragma unroll
  for (int m = 0; m < 4; ++m)
#pragma unroll
    for (int n = 0; n < 4; ++n) acc[m][n] = (f32x4){0.f, 0.f, 0.f, 0.f};

  stage(0, 0);
  __syncthreads();
  for (int ks = 0; ks < 32; ++ks) {
    const int cur = ks & 1;
    if (ks + 1 < 32) stage(ks + 1, cur ^ 1);
    short8 av[4], bv4[4];
#pragma unroll
    for (int m = 0; m < 4; ++m) {
      int r = wm + m * 16 + li;
      av[m] = *(const short8*)(As[cur] + r * 32 + (g ^ ((r >> 1) & 3)) * 8);
    }
#pragma unroll
    for (int n = 0; n < 4; ++n) {
      int r = wn + n * 16 + li;
      bv4[n] = *(const short8*)(Bs[cur] + r * 32 + (g ^ ((r >> 1) & 3)) * 8);
    }
    __builtin_amdgcn_s_setprio(1);
#pragma unroll
    for (int m = 0; m < 4; ++m)
#pragma unroll
      for (int n = 0; n < 4; ++n) acc[m][n] = mfma_bf16(av[m], bv4[n], acc[m][n]);
    __builtin_amdgcn_s_setprio(0);
    __syncthreads();
  }

  if (z < 2) {
    short* out = z == 0 ? Qh : Kh;
#pragma unroll
    for (int n = 0; n < 4; ++n) {
      int col = bn + wn + n * 16 + li;
      float bb = bias[col];
      int h = col >> 6, dk = col & 63;
#pragma unroll
      for (int m = 0; m < 4; ++m)
#pragma unroll
        for (int j = 0; j < 4; ++j) {
          int row = bm + wm + m * 16 + g * 4 + j;
          int b_ = row >> 11, s_ = row & 2047;
          out[(size_t)((b_ * NH + h) * S_LEN + s_) * DKH + dk] = f2bf(acc[m][n][j] + bb);
        }
    }
    if (z == 1) {
      // fused knorm: this wave covers full 64-col head (bn+wn)>>6 for rows wm..wm+63
      float sn[4][4];
#pragma unroll
      for (int m = 0; m < 4; ++m)
#pragma unroll
        for (int j = 0; j < 4; ++j) {
          float s = 0.f;
#pragma unroll
          for (int n = 0; n < 4; ++n) {
            float v = acc[m][n][j] + bias[bn + wn + n * 16 + li];
            s += v * v;
          }
          sn[m][j] = s;
        }
      // sum across the 16 li lanes -> full 64-col row norms
#pragma unroll
      for (int d = 1; d < 16; d <<= 1)
#pragma unroll
        for (int m = 0; m < 4; ++m)
#pragma unroll
          for (int j = 0; j < 4; ++j) sn[m][j] += __shfl_xor(sn[m][j], d);
      float mx = 0.f;
#pragma unroll
      for (int m = 0; m < 4; ++m)
#pragma unroll
        for (int j = 0; j < 4; ++j) mx = fmaxf(mx, sn[m][j]);
      mx = fmaxf(mx, __shfl_xor(mx, 16));
      mx = fmaxf(mx, __shfl_xor(mx, 32));
      if (lane == 0) {
        int head = (bn + wn) >> 6;
        int b_ = bm >> 11;
        atomicMax(&maxKn2[b_ * NH + head], __builtin_bit_cast(unsigned, mx));
      }
    }
  } else {  // V^T via two-pass LDS transpose, coalesced along s
    short* out = Vt;
    const int b_ = bm >> 11;
    const int sbase = bm & 2047;
#pragma unroll
    for (int ph = 0; ph < 2; ++ph) {
      __syncthreads();
      if ((wid & 1) == ph) {
#pragma unroll
        for (int n = 0; n < 4; ++n) {
          int colL = n * 16 + li;
          float bb = bias[bn + ph * 64 + colL];
#pragma unroll
          for (int m = 0; m < 4; ++m)
#pragma unroll
            for (int j = 0; j < 4; ++j) {
              int rowL = wm + m * 16 + g * 4 + j;
              T2[colL * 136 + rowL] = f2bf(acc[m][n][j] + bb);
            }
        }
      }
      __syncthreads();
      int dr = tid >> 2, qc = tid & 3;
      int nglob = bn + ph * 64 + dr;
      int h = nglob >> 6, dk = nglob & 63;
      short* op = out + (size_t)((b_ * NH + h) * DKH + dk) * S_LEN + sbase + qc * 32;
      const short* tp = T2 + dr * 136 + qc * 32;
#pragma unroll
      for (int i = 0; i < 4; ++i) *(short8*)(op + i * 8) = *(const short8*)(tp + i * 8);
    }
  }
}

// ---------------- output projection GEMM (double-buffered, 128x64 tile, 512 blocks): fp32 out ----------------
__global__ __launch_bounds__(256) void proj_out(const short* __restrict__ A, const short* __restrict__ W,
                                                const float* __restrict__ bias, float* __restrict__ out) {
  const int tid = threadIdx.x;
  const int wid = tid >> 6, lane = tid & 63;
  const int g = lane >> 4, li = lane & 15;
  const int wm = (wid >> 1) * 64, wn = (wid & 1) * 32;
  const int bn = blockIdx.x * 64, bm = blockIdx.y * 128;

  __shared__ __align__(16) short As[2][4096];
  __shared__ __align__(16) short Bs[2][2048];

  auto stage = [&](int ks, int pb) {
    const int k0 = ks * 32;
#pragma unroll
    for (int i = 0; i < 2; ++i) {
      int slot = i * 256 + tid;
      int r = slot >> 2, pos = slot & 3;
      int lch = pos ^ ((r >> 1) & 3);
      gld16(A + (size_t)(bm + r) * DMODEL + k0 + lch * 8, As[pb] + slot * 8);
    }
    {
      int slot = tid;
      int r = slot >> 2, pos = slot & 3;
      int lch = pos ^ ((r >> 1) & 3);
      gld16(W + (size_t)(bn + r) * DMODEL + k0 + lch * 8, Bs[pb] + slot * 8);
    }
  };

  f32x4 acc[4][2];
#pragma unroll
  for (int m = 0; m < 4; ++m)
#pragma unroll
    for (int n = 0; n < 2; ++n) acc[m][n] = (f32x4){0.f, 0.f, 0.f, 0.f};

  stage(0, 0);
  __syncthreads();
  for (int ks = 0; ks < 32; ++ks) {
    const int cur = ks & 1;
    if (ks + 1 < 32) stage(ks + 1, cur ^ 1);
    short8 av[4], bv4[2];
#pragma unroll
    for (int m = 0; m < 4; ++m) {
      int r = wm + m * 16 + li;
      av[m] = *(const short8*)(As[cur] + r * 32 + (g ^ ((r >> 1) & 3)) * 8);
    }
#pragma unroll
    for (int n = 0; n < 2; ++n) {
      int r = wn + n * 16 + li;
      bv4[n] = *(const short8*)(Bs[cur] + r * 32 + (g ^ ((r >> 1) & 3)) * 8);
    }
    __builtin_amdgcn_s_setprio(1);
#pragma unroll
    for (int m = 0; m < 4; ++m)
#pragma unroll
      for (int n = 0; n < 2; ++n) acc[m][n] = mfma_bf16(av[m], bv4[n], acc[m][n]);
    __builtin_amdgcn_s_setprio(0);
    __syncthreads();
  }

#pragma unroll
  for (int n = 0; n < 2; ++n) {
    int col = bn + wn + n * 16 + li;
    float bb = bias[col];
#pragma unroll
    for (int m = 0; m < 4; ++m)
#pragma unroll
      for (int j = 0; j < 4; ++j) {
        int row = bm + wm + m * 16 + g * 4 + j;
        out[(size_t)row * DMODEL + col] = acc[m][n][j] + bb;
      }
  }
}

// ---------------- fused attention (R11/R12-validated) ----------------
__global__ __launch_bounds__(256) void attn_fused(const short* __restrict__ Qh, const short* __restrict__ Kh,
                                                  const short* __restrict__ Vt,
                                                  const unsigned long long* __restrict__ maskb,
                                                  const unsigned* __restrict__ mall,
                                                  const unsigned* __restrict__ maxKn2,
                                                  float* __restrict__ pattn, short* __restrict__ xout) {
  const int tid = threadIdx.x;
  const int wid = tid >> 6, lane = tid & 63;
  const int g = lane >> 4, li = lane & 15;
  // XCD-chunked swizzle (1024 % 8 == 0, bijective)
  int swz = (blockIdx.x & 7) * 128 + (blockIdx.x >> 3);
  const int qblk = swz & 31;
  const int rest = swz >> 5;
  const int h = rest & 15, b = rest >> 4;
  const int bh = b * NH + h;
  const int q0 = qblk * 64 + wid * 16;

  const short* qptr = Qh + (size_t)(bh * S_LEN + q0 + li) * DKH;
  const short8 aq0 = *(const short8*)(qptr + g * 8);
  const short8 aq1 = *(const short8*)(qptr + 32 + g * 8);

  // ||q_row||^2 for row q0+li (exact values fed to MFMA)
  float qn2 = 0.f;
#pragma unroll
  for (int e = 0; e < 8; ++e) {
    float f0 = bf2f(aq0[e]), f1 = bf2f(aq1[e]);
    qn2 += f0 * f0 + f1 * f1;
  }
  qn2 += __shfl_xor(qn2, 16);
  qn2 += __shfl_xor(qn2, 32);
  const float mk = sqrtf(__builtin_bit_cast(float, maxKn2[bh]));

  float M2[4], lsum[4], off[4];
  unsigned ms[4];
#pragma unroll
  for (int j = 0; j < 4; ++j) {
    float qn = __shfl(qn2, g * 4 + j);
    M2[j] = sqrtf(qn) * mk * SC + 1.0f;  // Cauchy-Schwarz upper bound, +1 margin
    lsum[j] = 0.f;
    ms[j] = mall[b * S_LEN + q0 + g * 4 + j];
  }

  // LDS union: sweep1 two 128x64 K bufs (0..16384); sweep2 dbuf K(0..8192)/V(8192..16384) + Ps(16384..20480)
  __shared__ __align__(16) short SB[20480];

  auto stage1 = [&](int t) {
    short* dst = SB + (t & 1) * 8192;
#pragma unroll
    for (int i = 0; i < 4; ++i) {
      int slot = i * 256 + tid;
      int r = slot >> 3, pos = slot & 7;
      int lch = pos ^ (r & 7);
      gld16(Kh + (size_t)(bh * S_LEN + t * 128 + r) * DKH + lch * 8, dst + slot * 8);
    }
  };
  auto stage2 = [&](int kt) {
    const int pb = kt & 1;
    short* Kd = SB + pb * 4096;
    short* Vd = SB + 8192 + pb * 4096;
    const int k0 = kt * 64;
#pragma unroll
    for (int i = 0; i < 2; ++i) {
      int slot = i * 256 + tid;
      int r = slot >> 3, pos = slot & 7;
      int lch = pos ^ (r & 7);
      gld16(Kh + (size_t)(bh * S_LEN + k0 + r) * DKH + lch * 8, Kd + slot * 8);
      gld16(Vt + (size_t)(bh * DKH + r) * S_LEN + k0 + lch * 8, Vd + slot * 8);
    }
  };

  // ---- sweep 1: l = sum exp2(s2 - M2), 128 k-rows per iter, double-buffered ----
  stage1(0);
  __syncthreads();
  for (int t = 0; t < 16; ++t) {
    const short* Kc = SB + (t & 1) * 8192;
    if (t + 1 < 16) stage1(t + 1);
#pragma unroll
    for (int half = 0; half < 2; ++half) {
      f32x4 acc[4];
      __builtin_amdgcn_s_setprio(1);
#pragma unroll
      for (int nf = 0; nf < 4; ++nf) {
        acc[nf] = (f32x4){0.f, 0.f, 0.f, 0.f};
        int rB = half * 64 + nf * 16 + li;
        const short8 b0 = *(const short8*)(Kc + rB * 64 + ((0 + g) ^ (rB & 7)) * 8);
        const short8 b1 = *(const short8*)(Kc + rB * 64 + ((4 + g) ^ (rB & 7)) * 8);
        acc[nf] = mfma_bf16(aq0, b0, acc[nf]);
        acc[nf] = mfma_bf16(aq1, b1, acc[nf]);
      }
      __builtin_amdgcn_s_setprio(0);
#pragma unroll
      for (int j = 0; j < 4; ++j) {
        float s0 = acc[0][j] * SC - M2[j];
        float s1 = acc[1][j] * SC - M2[j];
        float s2 = acc[2][j] * SC - M2[j];
        float s3 = acc[3][j] * SC - M2[j];
        if (!((ms[j] >> (t * 2 + half)) & 1)) {
          unsigned long long mb = maskb[(size_t)(b * S_LEN + q0 + g * 4 + j) * 32 + t * 2 + half];
          if (!((mb >> li) & 1)) s0 = -INFINITY;
          if (!((mb >> (16 + li)) & 1)) s1 = -INFINITY;
          if (!((mb >> (32 + li)) & 1)) s2 = -INFINITY;
          if (!((mb >> (48 + li)) & 1)) s3 = -INFINITY;
        }
        lsum[j] += e2(s0) + e2(s1) + e2(s2) + e2(s3);
      }
    }
    __syncthreads();
  }
  // overlap: first sweep-2 staging flies during the reduction (safe: after last barrier)
  stage2(0);
  // reduce l across the 16 li lanes
#pragma unroll
  for (int d = 1; d < 16; d <<= 1)
#pragma unroll
    for (int j = 0; j < 4; ++j) lsum[j] += __shfl_xor(lsum[j], d);
#pragma unroll
  for (int j = 0; j < 4; ++j) off[j] = M2[j] + __builtin_amdgcn_logf(lsum[j]);  // p = exp2(acc*SC - off)

  // ---- sweep 2: p write + PV, double-buffered, normalized P in Ps (R6-validated order) ----
  f32x4 accx[4];
#pragma unroll
  for (int nf = 0; nf < 4; ++nf) accx[nf] = (f32x4){0.f, 0.f, 0.f, 0.f};

  __syncthreads();
  for (int kt = 0; kt < 32; ++kt) {
    const int k0 = kt * 64;
    const int cur = kt & 1;
    const short* Kc = SB + cur * 4096;
    const short* Vc = SB + 8192 + cur * 4096;
    short* Ps = SB + 16384;
    if (kt + 1 < 32) stage2(kt + 1);

    f32x4 acc[4];
    __builtin_amdgcn_s_setprio(1);
#pragma unroll
    for (int nf = 0; nf < 4; ++nf) {
      acc[nf] = (f32x4){0.f, 0.f, 0.f, 0.f};
      int rB = nf * 16 + li;
      const short8 b0 = *(const short8*)(Kc + rB * 64 + ((0 + g) ^ (rB & 7)) * 8);
      const short8 b1 = *(const short8*)(Kc + rB * 64 + ((4 + g) ^ (rB & 7)) * 8);
      acc[nf] = mfma_bf16(aq0, b0, acc[nf]);
      acc[nf] = mfma_bf16(aq1, b1, acc[nf]);
    }
    __builtin_amdgcn_s_setprio(0);

    // softmax -> per-wave bf16 NORMALIZED p tile in LDS (swizzled); linv folded into exponent
#pragma unroll
    for (int j = 0; j < 4; ++j) {
      const int qrow = q0 + g * 4 + j;
      bool full = (ms[j] >> kt) & 1;
      unsigned long long mb = full ? ~0ull : maskb[(size_t)(b * S_LEN + qrow) * 32 + kt];
      const int row = g * 4 + j;
#pragma unroll
      for (int nf = 0; nf < 4; ++nf) {
        float s = acc[nf][j] * SC - off[j];
        if (!full && !((mb >> (nf * 16 + li)) & 1)) s = -INFINITY;
        float p = e2(s);
        int col = nf * 16 + li;
        int sidx = row * 64 + (((col >> 3) ^ (row & 7)) * 8) + (col & 7);
        Ps[wid * 1024 + sidx] = f2bf(p);
      }
    }

    // PV on normalized p
    const short8 pa0 = *(const short8*)(Ps + wid * 1024 + li * 64 + ((0 + g) ^ (li & 7)) * 8);
    const short8 pa1 = *(const short8*)(Ps + wid * 1024 + li * 64 + ((4 + g) ^ (li & 7)) * 8);
    __builtin_amdgcn_s_setprio(1);
#pragma unroll
    for (int nf = 0; nf < 4; ++nf) {
      int rv = nf * 16 + li;
      const short8 v0 = *(const short8*)(Vc + rv * 64 + ((0 + g) ^ (rv & 7)) * 8);
      const short8 v1 = *(const short8*)(Vc + rv * 64 + ((4 + g) ^ (rv & 7)) * 8);
      accx[nf] = mfma_bf16(pa0, v0, accx[nf]);
      accx[nf] = mfma_bf16(pa1, v1, accx[nf]);
    }
    __builtin_amdgcn_s_setprio(0);

    // cooperative vectorized p_attn write AFTER PV (R6-validated position); nontemporal
    {
      const int rg = lane >> 4;
      const int c = (lane & 15) * 4;
#pragma unroll
      for (int s = 0; s < 4; ++s) {
        int r = s * 4 + rg;
        int chunk = (c >> 3) ^ (r & 7);
        sv4 pv4 = *(const sv4*)(Ps + wid * 1024 + r * 64 + chunk * 8 + (c & 7));
        f32x4 w4;
        w4[0] = bf2f(pv4[0]);
        w4[1] = bf2f(pv4[1]);
        w4[2] = bf2f(pv4[2]);
        w4[3] = bf2f(pv4[3]);
        __builtin_nontemporal_store(w4, (f32x4*)(pattn + (size_t)(bh * S_LEN + q0 + r) * S_LEN + k0 + c));
      }
    }
    __syncthreads();
  }

#pragma unroll
  for (int nf = 0; nf < 4; ++nf) {
    int d = nf * 16 + li;
#pragma unroll
    for (int j = 0; j < 4; ++j) {
      int q = q0 + g * 4 + j;
      xout[(size_t)(b * S_LEN + q) * DMODEL + h * DKH + d] = f2bf(accx[nf][j]);
    }
  }
}

extern "C" void kernel_launch(void* const* d_in, const int* in_sizes, int n_in,
                              void* d_out, int out_size, void* d_ws, size_t ws_size,
                              hipStream_t stream) {
  (void)in_sizes; (void)n_in; (void)out_size; (void)ws_size;
  const float* query = (const float*)d_in[0];
  const float* key = (const float*)d_in[1];
  const float* value = (const float*)d_in[2];
  const int* mask = (const int*)d_in[3];
  const float* wq = (const float*)d_in[4];
  const float* bq = (const float*)d_in[5];
  const float* wk = (const float*)d_in[6];
  const float* bk = (const float*)d_in[7];
  const float* wv = (const float*)d_in[8];
  const float* bv = (const float*)d_in[9];
  const float* wo = (const float*)d_in[10];
  const float* bo = (const float*)d_in[11];

  char* ws = (char*)d_ws;
  const size_t MB = 1u << 20;
  short* qb = (short*)(ws + 0 * MB);
  short* kb = (short*)(ws + 8 * MB);
  short* vb = (short*)(ws + 16 * MB);
  short* wqT = (short*)(ws + 24 * MB);
  short* wkT = (short*)(ws + 26 * MB);
  short* wvT = (short*)(ws + 28 * MB);
  short* woT = (short*)(ws + 30 * MB);
  short* Qh = (short*)(ws + 32 * MB);
  short* Kh = (short*)(ws + 40 * MB);
  short* Vt = (short*)(ws + 48 * MB);
  unsigned* maxKn2 = (unsigned*)(ws + 56 * MB);
  unsigned* mall = (unsigned*)(ws + 56 * MB + 64 * 1024);
  short* xb = (short*)(ws + 57 * MB);
  // maskb lives in its own region (58 MB+) — written by prep, read by attn
  unsigned long long* maskb = (unsigned long long*)(ws + 58 * MB);

  float* out_x = (float*)d_out;
  float* out_p = (float*)d_out + 4194304;

  prep_kernel<<<dim3(17408), 256, 0, stream>>>(query, key, value, mask, wq, wk, wv, wo,
                                               qb, kb, vb, wqT, wkT, wvT, woT, maskb, mall, maxKn2);
  proj_qkv<<<dim3(8, 32, 3), 256, 0, stream>>>(qb, kb, vb, wqT, wkT, wvT, bq, bk, bv, Qh, Kh, Vt, maxKn2);
  attn_fused<<<dim3(1024), 256, 0, stream>>>(Qh, Kh, Vt, maskb, mall, maxKn2, out_p, xb);
  proj_out<<<dim3(16, 32), 256, 0, stream>>>(xb, woT, bo, out_x);
}